// Round 6
// baseline (227.116 us; speedup 1.0000x reference)
//
#include <hip/hip_runtime.h>
#include <hip/hip_bf16.h>

#define BB 8
#define TT 512
#define SS 512
#define DD 512
#define HH 8

typedef __attribute__((ext_vector_type(8))) short bf16x8;
typedef __attribute__((ext_vector_type(4))) float f32x4;
typedef unsigned short u16;

__device__ __forceinline__ u16 f2b(float f) {
    __hip_bfloat16 h = __float2bfloat16(f);
    return *reinterpret_cast<u16*>(&h);
}
__device__ __forceinline__ float b2f(u16 v) {
    unsigned int u = ((unsigned int)v) << 16;
    return __builtin_bit_cast(float, u);
}
__device__ __forceinline__ void g2lds16(const void* g, void* l) {
    __builtin_amdgcn_global_load_lds(
        (const __attribute__((address_space(1))) void*)g,
        (__attribute__((address_space(3))) void*)l, 16, 0, 0);
}
template <int N> __device__ __forceinline__ void waitvm();
template <> __device__ __forceinline__ void waitvm<0>()  { asm volatile("s_waitcnt vmcnt(0)" ::: "memory"); }
template <> __device__ __forceinline__ void waitvm<4>()  { asm volatile("s_waitcnt vmcnt(4)" ::: "memory"); }
template <> __device__ __forceinline__ void waitvm<6>()  { asm volatile("s_waitcnt vmcnt(6)" ::: "memory"); }
template <> __device__ __forceinline__ void waitvm<8>()  { asm volatile("s_waitcnt vmcnt(8)" ::: "memory"); }
template <> __device__ __forceinline__ void waitvm<16>() { asm volatile("s_waitcnt vmcnt(16)" ::: "memory"); }
__device__ __forceinline__ void barrier_raw() {
    asm volatile("" ::: "memory");
    __builtin_amdgcn_s_barrier();
    asm volatile("" ::: "memory");
}

// ================= multi-segment f32 -> bf16 cast =================
struct CastSegs {
    const float* s[9];
    u16* d[9];
    int cum[10];
};
__global__ __launch_bounds__(256) void cast_multi(CastSegs sg) {
    const int total = sg.cum[9];
    for (int i = blockIdx.x * 256 + threadIdx.x; i < total; i += gridDim.x * 256) {
        int k = 0;
#pragma unroll
        for (int j = 1; j < 9; ++j) k += (i >= sg.cum[j]);
        const int loc = i - sg.cum[k];
        float4 v = ((const float4*)sg.s[k])[loc];
        ushort4 u;
        u.x = f2b(v.x); u.y = f2b(v.y); u.z = f2b(v.z); u.w = f2b(v.w);
        ((ushort4*)sg.d[k])[loc] = u;
    }
}

// WkT[h][d][e] = ca_in_w[(512 + h*64 + e)*512 + d]
__global__ __launch_bounds__(256) void wkt_kernel(const float* __restrict__ w,
                                                  u16* __restrict__ o) {
    const int idx = blockIdx.x * 256 + threadIdx.x;  // 262144 total
    const int h = idx >> 15, d = (idx >> 6) & 511, e = idx & 63;
    o[idx] = f2b(w[(size_t)(512 + h * 64 + e) * 512 + d]);
}

// ================= bf16 MFMA GEMM, dbuf prefetch, TM x TN tiles ==========
// C = epi(A(M,K) @ B(N,K)^T). 256 thr (2x2 waves). bf16 in/out.
template <int TM, int TN, bool RELU, bool GATE>
__global__ __launch_bounds__(256) void gemm_bf16(
    const u16* __restrict__ A, int lda, long az,
    const u16* __restrict__ Bw, int ldb, long bz,
    const float* __restrict__ bias, const float* __restrict__ biasB,
    const float* __restrict__ gate,
    u16* __restrict__ C, int ldo, long cz,
    int K, float alpha, float alphaB) {
    __shared__ __align__(16) u16 As[2][TM * 64];
    __shared__ __align__(16) u16 Bs[2][TN * 64];
    const int tid = threadIdx.x;
    const int wave = tid >> 6, lane = tid & 63;
    const int lm = lane & 15, lg = lane >> 4;
    const int wm = wave >> 1, wn = wave & 1;
    const int m0 = blockIdx.y * TM, n0 = blockIdx.x * TN;
    A += (size_t)blockIdx.z * az;
    Bw += (size_t)blockIdx.z * bz;
    C += (size_t)blockIdx.z * cz;
    constexpr int MI = TM / 32;
    constexpr int FN = TN / 32;
    constexpr int LPS = MI + FN;

    f32x4 acc[MI][FN];
#pragma unroll
    for (int mi = 0; mi < MI; ++mi)
#pragma unroll
        for (int ni = 0; ni < FN; ++ni) acc[mi][ni] = (f32x4){0.f, 0.f, 0.f, 0.f};

    const int srow = lane >> 3;
    const int sbyte = ((lane & 7) << 4) ^ (srow << 4);
    const int xk = (lm & 7) << 4;

    auto stage = [&](int buf, int kt) {
#pragma unroll
        for (int j = 0; j < MI; ++j) {
            const int r = wave * (TM / 4) + j * 8;
            g2lds16((const char*)(A + (size_t)(m0 + r + srow) * lda + kt) + sbyte,
                    (char*)As[buf] + (size_t)r * 128);
        }
#pragma unroll
        for (int j = 0; j < FN; ++j) {
            const int r = wave * (TN / 4) + j * 8;
            g2lds16((const char*)(Bw + (size_t)(n0 + r + srow) * ldb + kt) + sbyte,
                    (char*)Bs[buf] + (size_t)r * 128);
        }
    };

    stage(0, 0);
    const int NK = K >> 6;
    for (int t = 0; t < NK; ++t) {
        const int cur = t & 1;
        if (t + 1 < NK) { stage(cur ^ 1, (t + 1) << 6); waitvm<LPS>(); }
        else            { waitvm<0>(); }
        barrier_raw();
#pragma unroll
        for (int kh = 0; kh < 2; ++kh) {
            const int cb = kh * 64 + lg * 16;
            bf16x8 af[MI], bfr[FN];
#pragma unroll
            for (int mi = 0; mi < MI; ++mi) {
                const int row = wm * (TM / 2) + mi * 16 + lm;
                af[mi] = *(const bf16x8*)((const char*)As[cur] + row * 128 + (cb ^ xk));
            }
#pragma unroll
            for (int ni = 0; ni < FN; ++ni) {
                const int row = wn * (TN / 2) + ni * 16 + lm;
                bfr[ni] = *(const bf16x8*)((const char*)Bs[cur] + row * 128 + (cb ^ xk));
            }
#pragma unroll
            for (int mi = 0; mi < MI; ++mi)
#pragma unroll
                for (int ni = 0; ni < FN; ++ni)
                    acc[mi][ni] = __builtin_amdgcn_mfma_f32_16x16x32_bf16(
                        af[mi], bfr[ni], acc[mi][ni], 0, 0, 0);
        }
        barrier_raw();
    }

    const float* bp = blockIdx.z ? biasB : bias;
    const float al = blockIdx.z ? alphaB : alpha;
#pragma unroll
    for (int mi = 0; mi < MI; ++mi)
#pragma unroll
        for (int ni = 0; ni < FN; ++ni)
#pragma unroll
            for (int r = 0; r < 4; ++r) {
                const int m = m0 + wm * (TM / 2) + mi * 16 + lg * 4 + r;
                const int n = n0 + wn * (TN / 2) + ni * 16 + lm;
                float v = acc[mi][ni][r];
                if constexpr (GATE) v *= gate[(size_t)(m & 511) * 512 + n];
                else                v = (v + bp[n]) * al;
                if constexpr (RELU) v = fmaxf(v, 0.f);
                C[(size_t)m * ldo + n] = f2b(v);
            }
}

// ================= self flash attention (verified r3) =================
__global__ __launch_bounds__(256) void flash_self(const u16* __restrict__ QKV,
                                                  u16* __restrict__ out) {
    const int t0 = blockIdx.x * 64, h = blockIdx.y, b = blockIdx.z;
    const int tid = threadIdx.x, wave = tid >> 6, lane = tid & 63;
    const int lm = lane & 15, lg = lane >> 4;
    __shared__ __align__(16) u16 Ks[32 * 64];
    __shared__ __align__(16) u16 Vt[64][40];
    __shared__ __align__(16) u16 P[4][16][40];

    const int tw = t0 + wave * 16;
    const size_t qrow = (size_t)(b * TT + tw + lm) * 1536 + h * 64;
    bf16x8 qf[2];
    qf[0] = *(const bf16x8*)(QKV + qrow + lg * 8);
    qf[1] = *(const bf16x8*)(QKV + qrow + 32 + lg * 8);

    float m_run[4], l_run[4];
    f32x4 oacc[4];
#pragma unroll
    for (int r = 0; r < 4; ++r) { m_run[r] = -3e38f; l_run[r] = 0.f; }
#pragma unroll
    for (int nt = 0; nt < 4; ++nt) oacc[nt] = (f32x4){0.f, 0.f, 0.f, 0.f};

    const int srow = lane >> 3, sbyte = ((lane & 7) << 4) ^ (srow << 4);
    const int xk = (lm & 7) << 4;
    const int smax = t0 + 64;
    for (int s0 = 0; s0 < smax; s0 += 32) {
        if (s0) __syncthreads();
        g2lds16((const char*)(QKV + (size_t)(b * TT + s0 + wave * 8 + srow) * 1536 +
                              512 + h * 64) + sbyte,
                (char*)Ks + wave * 1024);
        {
            const int s = tid & 31, d0 = (tid >> 5) * 8;
            bf16x8 vv = *(const bf16x8*)(QKV + (size_t)(b * TT + s0 + s) * 1536 +
                                         1024 + h * 64 + d0);
#pragma unroll
            for (int j = 0; j < 8; ++j) Vt[d0 + j][s] = (u16)vv[j];
        }
        __syncthreads();
        if (s0 <= tw + 15) {
            f32x4 sc0 = (f32x4){0.f, 0.f, 0.f, 0.f};
            f32x4 sc1 = (f32x4){0.f, 0.f, 0.f, 0.f};
#pragma unroll
            for (int f = 0; f < 2; ++f) {
                const int cb = f * 64 + lg * 16;
                bf16x8 k0 = *(const bf16x8*)((const char*)Ks + lm * 128 + (cb ^ xk));
                bf16x8 k1 = *(const bf16x8*)((const char*)Ks + (16 + lm) * 128 + (cb ^ xk));
                sc0 = __builtin_amdgcn_mfma_f32_16x16x32_bf16(qf[f], k0, sc0, 0, 0, 0);
                sc1 = __builtin_amdgcn_mfma_f32_16x16x32_bf16(qf[f], k1, sc1, 0, 0, 0);
            }
            float sv0[4], sv1[4], tm[4];
#pragma unroll
            for (int r = 0; r < 4; ++r) {
                const int t = tw + lg * 4 + r;
                sv0[r] = sc0[r] * 0.125f + ((s0 + lm) <= t ? 0.f : -1e9f);
                sv1[r] = sc1[r] * 0.125f + ((s0 + 16 + lm) <= t ? 0.f : -1e9f);
                tm[r] = fmaxf(sv0[r], sv1[r]);
            }
#pragma unroll
            for (int off = 1; off < 16; off <<= 1)
#pragma unroll
                for (int r = 0; r < 4; ++r) tm[r] = fmaxf(tm[r], __shfl_xor(tm[r], off));
            float fac[4], rs[4];
#pragma unroll
            for (int r = 0; r < 4; ++r) {
                const float mn = fmaxf(m_run[r], tm[r]);
                fac[r] = __expf(m_run[r] - mn);
                m_run[r] = mn;
                const float p0 = __expf(sv0[r] - mn);
                const float p1 = __expf(sv1[r] - mn);
                P[wave][lg * 4 + r][lm] = f2b(p0);
                P[wave][lg * 4 + r][16 + lm] = f2b(p1);
                rs[r] = p0 + p1;
            }
#pragma unroll
            for (int off = 1; off < 16; off <<= 1)
#pragma unroll
                for (int r = 0; r < 4; ++r) rs[r] += __shfl_xor(rs[r], off);
#pragma unroll
            for (int r = 0; r < 4; ++r) l_run[r] = l_run[r] * fac[r] + rs[r];
#pragma unroll
            for (int nt = 0; nt < 4; ++nt)
#pragma unroll
                for (int r = 0; r < 4; ++r) oacc[nt][r] *= fac[r];
            const bf16x8 pf = *(const bf16x8*)&P[wave][lm][lg * 8];
#pragma unroll
            for (int nt = 0; nt < 4; ++nt) {
                const bf16x8 vf = *(const bf16x8*)&Vt[nt * 16 + lm][lg * 8];
                oacc[nt] = __builtin_amdgcn_mfma_f32_16x16x32_bf16(pf, vf, oacc[nt], 0, 0, 0);
            }
        }
    }
#pragma unroll
    for (int nt = 0; nt < 4; ++nt)
#pragma unroll
        for (int r = 0; r < 4; ++r)
            out[(size_t)(b * TT + tw + lg * 4 + r) * DD + h * 64 + nt * 16 + lm] =
                f2b(oacc[nt][r] / l_run[r]);
}

// ======== cross flash attention v3: 2 waves x 32 q, single-buffer K =======
// QW: (B*T,4096) bf16, head h at col h*512. Kmem: (B*S,512). CV col h*64.
// LDS 48KB -> 3 blocks/CU. K-stage for chunk c+1 issued after the post-QK^T
// barrier and drained after softmax+PV (overlapped); V dbuf via registers.
__global__ __launch_bounds__(128) void flash_cross(
    const u16* __restrict__ QW, const u16* __restrict__ Kmem,
    const u16* __restrict__ CV, u16* __restrict__ out) {
    const int t0 = blockIdx.x * 64, h = blockIdx.y, b = blockIdx.z;
    const int tid = threadIdx.x, wave = tid >> 6, lane = tid & 63;
    const int lm = lane & 15, lg = lane >> 4;
    __shared__ __align__(16) u16 Ks[32 * 512];   // 32 KB (single buffer)
    __shared__ __align__(16) u16 Vt[2][64][40];  // 10 KB
    __shared__ __align__(16) u16 P[2][32][40];   // 5 KB

    const int tq = t0 + wave * 32;
    const size_t qrowA = (size_t)(b * TT + tq + lm) * 4096 + h * 512;
    const size_t qrowB = qrowA + (size_t)16 * 4096;
    bf16x8 qfA[16], qfB[16];
#pragma unroll
    for (int f = 0; f < 16; ++f) {
        qfA[f] = *(const bf16x8*)(QW + qrowA + f * 32 + lg * 8);
        qfB[f] = *(const bf16x8*)(QW + qrowB + f * 32 + lg * 8);
    }

    float mA[4], lA[4], mB[4], lB[4];
    f32x4 oA[4], oB[4];
#pragma unroll
    for (int r = 0; r < 4; ++r) { mA[r] = -3e38f; lA[r] = 0.f; mB[r] = -3e38f; lB[r] = 0.f; }
#pragma unroll
    for (int nt = 0; nt < 4; ++nt) { oA[nt] = (f32x4){0.f,0.f,0.f,0.f}; oB[nt] = (f32x4){0.f,0.f,0.f,0.f}; }

    const int xk = (lm & 7) << 4;
    const int sV = tid & 31, dV = (tid >> 5) * 16;

    auto stageK = [&](int s0) {
#pragma unroll
        for (int j = 0; j < 16; ++j) {
            const int row = wave * 16 + j;
            g2lds16((const char*)(Kmem + ((size_t)b * SS + s0 + row) * 512) +
                        ((lane * 16) ^ ((j & 7) << 4)),
                    (char*)Ks + row * 1024);
        }
    };
    auto vload0 = [&](int s0) -> bf16x8 {
        return *(const bf16x8*)(CV + ((size_t)b * SS + s0 + sV) * 512 + h * 64 + dV);
    };
    auto vload1 = [&](int s0) -> bf16x8 {
        return *(const bf16x8*)(CV + ((size_t)b * SS + s0 + sV) * 512 + h * 64 + dV + 8);
    };

    // prologue: V chunk0 + K chunk0
    bf16x8 vr0 = vload0(0), vr1 = vload1(0);
    stageK(0);
    waitvm<0>();
#pragma unroll
    for (int j = 0; j < 8; ++j) {
        Vt[0][dV + j][sV] = (u16)vr0[j];
        Vt[0][dV + 8 + j][sV] = (u16)vr1[j];
    }
    asm volatile("s_waitcnt lgkmcnt(0)" ::: "memory");
    barrier_raw();

    for (int c = 0; c < 16; ++c) {
        const int cur = c & 1;
        // ---- QK^T: 32q x 32s (reads Ks) ----
        f32x4 sA0 = (f32x4){0.f,0.f,0.f,0.f}, sA1 = (f32x4){0.f,0.f,0.f,0.f};
        f32x4 sB0 = (f32x4){0.f,0.f,0.f,0.f}, sB1 = (f32x4){0.f,0.f,0.f,0.f};
#pragma unroll
        for (int f = 0; f < 16; ++f) {
            const int cb = f * 64 + lg * 16;
            bf16x8 k0 = *(const bf16x8*)((const char*)Ks + lm * 1024 + (cb ^ xk));
            bf16x8 k1 = *(const bf16x8*)((const char*)Ks + (16 + lm) * 1024 + (cb ^ xk));
            sA0 = __builtin_amdgcn_mfma_f32_16x16x32_bf16(qfA[f], k0, sA0, 0, 0, 0);
            sA1 = __builtin_amdgcn_mfma_f32_16x16x32_bf16(qfA[f], k1, sA1, 0, 0, 0);
            sB0 = __builtin_amdgcn_mfma_f32_16x16x32_bf16(qfB[f], k0, sB0, 0, 0, 0);
            sB1 = __builtin_amdgcn_mfma_f32_16x16x32_bf16(qfB[f], k1, sB1, 0, 0, 0);
        }
        barrier_raw();   // all waves done reading Ks chunk c
        if (c < 15) {
            // issue next V loads (oldest in queue) then next K stage (16 gloads)
            vr0 = vload0((c + 1) * 32);
            vr1 = vload1((c + 1) * 32);
            stageK((c + 1) * 32);
        }
        // ---- online softmax (VALU; covers the stage latency) ----
        float tmA[4], tmB[4];
#pragma unroll
        for (int r = 0; r < 4; ++r) {
            tmA[r] = fmaxf(sA0[r], sA1[r]);
            tmB[r] = fmaxf(sB0[r], sB1[r]);
        }
#pragma unroll
        for (int off = 1; off < 16; off <<= 1)
#pragma unroll
            for (int r = 0; r < 4; ++r) {
                tmA[r] = fmaxf(tmA[r], __shfl_xor(tmA[r], off));
                tmB[r] = fmaxf(tmB[r], __shfl_xor(tmB[r], off));
            }
        float facA[4], facB[4], rsA[4], rsB[4];
#pragma unroll
        for (int r = 0; r < 4; ++r) {
            const float mnA = fmaxf(mA[r], tmA[r]);
            facA[r] = __expf(mA[r] - mnA); mA[r] = mnA;
            const float pA0 = __expf(sA0[r] - mnA);
            const float pA1 = __expf(sA1[r] - mnA);
            P[wave][lg * 4 + r][lm] = f2b(pA0);
            P[wave][lg * 4 + r][16 + lm] = f2b(pA1);
            rsA[r] = pA0 + pA1;
            const float mnB = fmaxf(mB[r], tmB[r]);
            facB[r] = __expf(mB[r] - mnB); mB[r] = mnB;
            const float pB0 = __expf(sB0[r] - mnB);
            const float pB1 = __expf(sB1[r] - mnB);
            P[wave][16 + lg * 4 + r][lm] = f2b(pB0);
            P[wave][16 + lg * 4 + r][16 + lm] = f2b(pB1);
            rsB[r] = pB0 + pB1;
        }
#pragma unroll
        for (int off = 1; off < 16; off <<= 1)
#pragma unroll
            for (int r = 0; r < 4; ++r) {
                rsA[r] += __shfl_xor(rsA[r], off);
                rsB[r] += __shfl_xor(rsB[r], off);
            }
#pragma unroll
        for (int r = 0; r < 4; ++r) {
            lA[r] = lA[r] * facA[r] + rsA[r];
            lB[r] = lB[r] * facB[r] + rsB[r];
        }
#pragma unroll
        for (int nt = 0; nt < 4; ++nt)
#pragma unroll
            for (int r = 0; r < 4; ++r) { oA[nt][r] *= facA[r]; oB[nt][r] *= facB[r]; }
        // ---- PV (reads P[wave], Vt[cur]) ----
        const bf16x8 pfA = *(const bf16x8*)&P[wave][lm][lg * 8];
        const bf16x8 pfB = *(const bf16x8*)&P[wave][16 + lm][lg * 8];
#pragma unroll
        for (int nt = 0; nt < 4; ++nt) {
            const bf16x8 vf = *(const bf16x8*)&Vt[cur][nt * 16 + lm][lg * 8];
            oA[nt] = __builtin_amdgcn_mfma_f32_16x16x32_bf16(pfA, vf, oA[nt], 0, 0, 0);
            oB[nt] = __builtin_amdgcn_mfma_f32_16x16x32_bf16(pfB, vf, oB[nt], 0, 0, 0);
        }
        if (c < 15) {
            waitvm<16>();  // the 2 V loads (oldest of 18) have returned
#pragma unroll
            for (int j = 0; j < 8; ++j) {
                Vt[cur ^ 1][dV + j][sV] = (u16)vr0[j];
                Vt[cur ^ 1][dV + 8 + j][sV] = (u16)vr1[j];
            }
            waitvm<0>();   // K stage for chunk c+1 fully landed
            asm volatile("s_waitcnt lgkmcnt(0)" ::: "memory");
            barrier_raw();
        }
    }
#pragma unroll
    for (int nt = 0; nt < 4; ++nt)
#pragma unroll
        for (int r = 0; r < 4; ++r) {
            out[(size_t)(b * TT + tq + lg * 4 + r) * DD + h * 64 + nt * 16 + lm] =
                f2b(oA[nt][r] / lA[r]);
            out[(size_t)(b * TT + tq + 16 + lg * 4 + r) * DD + h * 64 + nt * 16 + lm] =
                f2b(oB[nt][r] / lB[r]);
        }
}

// ================= fused residual + LayerNorm =================
template <bool R1B>
__global__ __launch_bounds__(256) void add_ln(
    const void* __restrict__ R1v, const u16* __restrict__ R2,
    const float* __restrict__ g, const float* __restrict__ bta,
    float* __restrict__ outf, u16* __restrict__ outb) {
    const int row = blockIdx.x, tid = threadIdx.x;
    float x0, x1;
    if constexpr (R1B) {
        ushort2 a = ((const ushort2*)((const u16*)R1v + (size_t)row * DD))[tid];
        x0 = b2f(a.x); x1 = b2f(a.y);
    } else {
        float2 a = ((const float2*)((const float*)R1v + (size_t)row * DD))[tid];
        x0 = a.x; x1 = a.y;
    }
    ushort2 c = ((const ushort2*)(R2 + (size_t)row * DD))[tid];
    x0 += b2f(c.x); x1 += b2f(c.y);

    __shared__ float2 red[256];
    red[tid] = make_float2(x0 + x1, x0 * x0 + x1 * x1);
    __syncthreads();
#pragma unroll
    for (int o = 128; o > 0; o >>= 1) {
        if (tid < o) {
            red[tid].x += red[tid + o].x;
            red[tid].y += red[tid + o].y;
        }
        __syncthreads();
    }
    const float mean = red[0].x * (1.f / 512.f);
    const float var = red[0].y * (1.f / 512.f) - mean * mean;
    const float rstd = rsqrtf(var + 1e-5f);
    const int i = tid * 2;
    const float y0 = (x0 - mean) * rstd * g[i] + bta[i];
    const float y1 = (x1 - mean) * rstd * g[i + 1] + bta[i + 1];
    if (outf) ((float2*)(outf + (size_t)row * DD))[tid] = make_float2(y0, y1);
    if (outb) {
        ushort2 ub; ub.x = f2b(y0); ub.y = f2b(y1);
        ((ushort2*)(outb + (size_t)row * DD))[tid] = ub;
    }
}

extern "C" void kernel_launch(void* const* d_in, const int* in_sizes, int n_in,
                              void* d_out, int out_size, void* d_ws, size_t ws_size,
                              hipStream_t stream) {
    const float* tgt      = (const float*)d_in[0];
    const float* memory   = (const float*)d_in[1];
    const float* gate     = (const float*)d_in[3];
    const float* sa_in_w  = (const float*)d_in[4];
    const float* sa_in_b  = (const float*)d_in[5];
    const float* sa_out_w = (const float*)d_in[6];
    const float* sa_out_b = (const float*)d_in[7];
    const float* ca_in_w  = (const float*)d_in[8];
    const float* ca_in_b  = (const float*)d_in[9];
    const float* ca_out_w = (const float*)d_in[10];
    const float* ca_out_b = (const float*)d_in[11];
    const float* ff1_w    = (const float*)d_in[12];
    const float* ff1_b    = (const float*)d_in[13];
    const float* ff2_w    = (const float*)d_in[14];
    const float* ff2_b    = (const float*)d_in[15];
    const float* ln1_g    = (const float*)d_in[16];
    const float* ln1_b    = (const float*)d_in[17];
    const float* ln2_g    = (const float*)d_in[18];
    const float* ln2_b    = (const float*)d_in[19];
    const float* ln3_g    = (const float*)d_in[20];
    const float* ln3_b    = (const float*)d_in[21];

    // ---- workspace layout (u16 units) ----
    u16* ws16     = (u16*)d_ws;
    u16* QKVb     = ws16;                    // 6291456
    u16* sa_preb  = ws16 + 6291456;          // 2097152
    u16* PRJb     = ws16 + 8388608;          // 2097152
    u16* X1b      = ws16 + 10485760;         // 2097152
    u16* memb     = ws16 + 12582912;         // 2097152
    u16* CQb      = ws16 + 14680064;         // 2097152
    u16* CVb      = ws16 + 16777216;         // 2097152
    u16* QW       = ws16 + 18874368;         // 16777216 (4096 x 4096)
    u16* ca_preb  = ws16 + 35651584;         // 2097152
    u16* PRJ2b    = ws16 + 37748736;         // 2097152
    u16* X2b      = ws16 + 39845888;         // 2097152
    u16* HHb      = ws16 + 41943040;         // 8388608
    u16* F1b      = ws16 + 50331648;         // 2097152
    u16* Wreg     = ws16 + 52428800;
    u16* sa_in_wb = Wreg;                    // 786432
    u16* sa_out_wb= Wreg + 786432;           // 262144
    u16* ca_wq_b  = Wreg + 1048576;          // 262144
    u16* ca_wv_b  = Wreg + 1310720;          // 262144
    u16* WkT      = Wreg + 1572864;          // 262144
    u16* ca_out_wb= Wreg + 1835008;          // 262144
    u16* ff1_wb   = Wreg + 2097152;          // 1048576
    u16* ff2_wb   = Wreg + 3145728;          // 1048576
    u16* tgtb     = ws16 + 56623104;         // 2097152
    float* outf   = (float*)d_out;

    const dim3 blk(256);

    // 0. casts
    CastSegs sg;
    sg.s[0]=tgt; sg.s[1]=memory; sg.s[2]=sa_in_w; sg.s[3]=sa_out_w;
    sg.s[4]=ca_in_w; sg.s[5]=ca_in_w + (size_t)1024*512; sg.s[6]=ca_out_w;
    sg.s[7]=ff1_w; sg.s[8]=ff2_w;
    sg.d[0]=tgtb; sg.d[1]=memb; sg.d[2]=sa_in_wb; sg.d[3]=sa_out_wb;
    sg.d[4]=ca_wq_b; sg.d[5]=ca_wv_b; sg.d[6]=ca_out_wb;
    sg.d[7]=ff1_wb; sg.d[8]=ff2_wb;
    {
        const int n4[9] = {524288,524288,196608,65536,65536,65536,65536,262144,262144};
        int c = 0;
        for (int i = 0; i < 9; ++i) { sg.cum[i] = c; c += n4[i]; }
        sg.cum[9] = c;
    }
    cast_multi<<<2048, blk, 0, stream>>>(sg);
    wkt_kernel<<<1024, blk, 0, stream>>>(ca_in_w, WkT);

    // 1. QKV (4096,1536)
    gemm_bf16<128,128,false,false><<<dim3(12,32,1), blk, 0, stream>>>(
        tgtb,512,0, sa_in_wb,512,0, sa_in_b,sa_in_b,nullptr,
        QKVb,1536,0, 512, 1.f,1.f);
    // 2. self flash -> sa_preb
    flash_self<<<dim3(8,8,8), blk, 0, stream>>>(QKVb, sa_preb);
    // 3. proj1
    gemm_bf16<64,64,false,false><<<dim3(8,64,1), blk, 0, stream>>>(
        sa_preb,512,0, sa_out_wb,512,0, sa_out_b,sa_out_b,nullptr,
        PRJb,512,0, 512, 1.f,1.f);
    // 4. LN1 -> X1b
    add_ln<false><<<4096, blk, 0, stream>>>(tgt, PRJb, ln1_g, ln1_b, nullptr, X1b);
    // 5. cq (z=0, alpha .125) + cv (z=1) batched
    gemm_bf16<64,64,false,false><<<dim3(8,64,2), blk, 0, stream>>>(
        X1b,512,2097152, ca_wq_b,512,262144, ca_in_b, ca_in_b+1024, nullptr,
        CQb,512,2097152, 512, 0.125f, 1.f);
    // 6. qWg all heads (z=8, K=64) -> QW (4096,4096)
    gemm_bf16<64,64,false,true><<<dim3(8,64,8), blk, 0, stream>>>(
        CQb,512,64, WkT,64,32768, nullptr,nullptr,gate,
        QW,4096,512, 64, 1.f,1.f);
    // 7. cross flash (all heads) -> ca_preb
    flash_cross<<<dim3(8,8,8), dim3(128), 0, stream>>>(QW, memb, CVb, ca_preb);
    // 8. proj2
    gemm_bf16<64,64,false,false><<<dim3(8,64,1), blk, 0, stream>>>(
        ca_preb,512,0, ca_out_wb,512,0, ca_out_b,ca_out_b,nullptr,
        PRJ2b,512,0, 512, 1.f,1.f);
    // 9. LN2 -> X2b
    add_ln<true><<<4096, blk, 0, stream>>>(X1b, PRJ2b, ln2_g, ln2_b, nullptr, X2b);
    // 10. ff1 + relu -> HHb
    gemm_bf16<128,128,true,false><<<dim3(16,32,1), blk, 0, stream>>>(
        X2b,512,0, ff1_wb,512,0, ff1_b,ff1_b,nullptr,
        HHb,2048,0, 512, 1.f,1.f);
    // 11. ff2 -> F1b
    gemm_bf16<64,64,false,false><<<dim3(8,64,1), blk, 0, stream>>>(
        HHb,2048,0, ff2_wb,2048,0, ff2_b,ff2_b,nullptr,
        F1b,512,0, 2048, 1.f,1.f);
    // 12. LN3 -> d_out
    add_ln<true><<<4096, blk, 0, stream>>>(X2b, F1b, ln3_g, ln3_b, outf, nullptr);

    (void)in_sizes; (void)n_in; (void)out_size; (void)ws_size;
}

// Round 7
// 214.913 us; speedup vs baseline: 1.0568x; 1.0568x over previous
//
#include <hip/hip_runtime.h>
#include <hip/hip_bf16.h>

#define BB 8
#define TT 512
#define SS 512
#define DD 512
#define HH 8

typedef __attribute__((ext_vector_type(8))) short bf16x8;
typedef __attribute__((ext_vector_type(4))) float f32x4;
typedef unsigned short u16;

__device__ __forceinline__ u16 f2b(float f) {
    __hip_bfloat16 h = __float2bfloat16(f);
    return *reinterpret_cast<u16*>(&h);
}
__device__ __forceinline__ float b2f(u16 v) {
    unsigned int u = ((unsigned int)v) << 16;
    return __builtin_bit_cast(float, u);
}
__device__ __forceinline__ void g2lds16(const void* g, void* l) {
    __builtin_amdgcn_global_load_lds(
        (const __attribute__((address_space(1))) void*)g,
        (__attribute__((address_space(3))) void*)l, 16, 0, 0);
}
template <int N> __device__ __forceinline__ void waitvm();
template <> __device__ __forceinline__ void waitvm<0>()  { asm volatile("s_waitcnt vmcnt(0)" ::: "memory"); }
template <> __device__ __forceinline__ void waitvm<4>()  { asm volatile("s_waitcnt vmcnt(4)" ::: "memory"); }
template <> __device__ __forceinline__ void waitvm<6>()  { asm volatile("s_waitcnt vmcnt(6)" ::: "memory"); }
template <> __device__ __forceinline__ void waitvm<8>()  { asm volatile("s_waitcnt vmcnt(8)" ::: "memory"); }
__device__ __forceinline__ void barrier_raw() {
    asm volatile("" ::: "memory");
    __builtin_amdgcn_s_barrier();
    asm volatile("" ::: "memory");
}

// ================= multi-segment f32 -> bf16 cast =================
struct CastSegs {
    const float* s[9];
    u16* d[9];
    int cum[10];
};
__global__ __launch_bounds__(256) void cast_multi(CastSegs sg) {
    const int total = sg.cum[9];
    for (int i = blockIdx.x * 256 + threadIdx.x; i < total; i += gridDim.x * 256) {
        int k = 0;
#pragma unroll
        for (int j = 1; j < 9; ++j) k += (i >= sg.cum[j]);
        const int loc = i - sg.cum[k];
        float4 v = ((const float4*)sg.s[k])[loc];
        ushort4 u;
        u.x = f2b(v.x); u.y = f2b(v.y); u.z = f2b(v.z); u.w = f2b(v.w);
        ((ushort4*)sg.d[k])[loc] = u;
    }
}

// WkT[h][d][e] = ca_in_w[(512 + h*64 + e)*512 + d]
__global__ __launch_bounds__(256) void wkt_kernel(const float* __restrict__ w,
                                                  u16* __restrict__ o) {
    const int idx = blockIdx.x * 256 + threadIdx.x;  // 262144 total
    const int h = idx >> 15, d = (idx >> 6) & 511, e = idx & 63;
    o[idx] = f2b(w[(size_t)(512 + h * 64 + e) * 512 + d]);
}

// ================= bf16 MFMA GEMM, dbuf prefetch, TM x TN tiles ==========
// C = epi(A(M,K) @ B(N,K)^T). 256 thr (2x2 waves). bf16 in/out.
template <int TM, int TN, bool RELU, bool GATE>
__global__ __launch_bounds__(256) void gemm_bf16(
    const u16* __restrict__ A, int lda, long az,
    const u16* __restrict__ Bw, int ldb, long bz,
    const float* __restrict__ bias, const float* __restrict__ biasB,
    const float* __restrict__ gate,
    u16* __restrict__ C, int ldo, long cz,
    int K, float alpha, float alphaB) {
    __shared__ __align__(16) u16 As[2][TM * 64];
    __shared__ __align__(16) u16 Bs[2][TN * 64];
    const int tid = threadIdx.x;
    const int wave = tid >> 6, lane = tid & 63;
    const int lm = lane & 15, lg = lane >> 4;
    const int wm = wave >> 1, wn = wave & 1;
    const int m0 = blockIdx.y * TM, n0 = blockIdx.x * TN;
    A += (size_t)blockIdx.z * az;
    Bw += (size_t)blockIdx.z * bz;
    C += (size_t)blockIdx.z * cz;
    constexpr int MI = TM / 32;
    constexpr int FN = TN / 32;
    constexpr int LPS = MI + FN;

    f32x4 acc[MI][FN];
#pragma unroll
    for (int mi = 0; mi < MI; ++mi)
#pragma unroll
        for (int ni = 0; ni < FN; ++ni) acc[mi][ni] = (f32x4){0.f, 0.f, 0.f, 0.f};

    const int srow = lane >> 3;
    const int sbyte = ((lane & 7) << 4) ^ (srow << 4);
    const int xk = (lm & 7) << 4;

    auto stage = [&](int buf, int kt) {
#pragma unroll
        for (int j = 0; j < MI; ++j) {
            const int r = wave * (TM / 4) + j * 8;
            g2lds16((const char*)(A + (size_t)(m0 + r + srow) * lda + kt) + sbyte,
                    (char*)As[buf] + (size_t)r * 128);
        }
#pragma unroll
        for (int j = 0; j < FN; ++j) {
            const int r = wave * (TN / 4) + j * 8;
            g2lds16((const char*)(Bw + (size_t)(n0 + r + srow) * ldb + kt) + sbyte,
                    (char*)Bs[buf] + (size_t)r * 128);
        }
    };

    stage(0, 0);
    const int NK = K >> 6;
    for (int t = 0; t < NK; ++t) {
        const int cur = t & 1;
        if (t + 1 < NK) { stage(cur ^ 1, (t + 1) << 6); waitvm<LPS>(); }
        else            { waitvm<0>(); }
        barrier_raw();
#pragma unroll
        for (int kh = 0; kh < 2; ++kh) {
            const int cb = kh * 64 + lg * 16;
            bf16x8 af[MI], bfr[FN];
#pragma unroll
            for (int mi = 0; mi < MI; ++mi) {
                const int row = wm * (TM / 2) + mi * 16 + lm;
                af[mi] = *(const bf16x8*)((const char*)As[cur] + row * 128 + (cb ^ xk));
            }
#pragma unroll
            for (int ni = 0; ni < FN; ++ni) {
                const int row = wn * (TN / 2) + ni * 16 + lm;
                bfr[ni] = *(const bf16x8*)((const char*)Bs[cur] + row * 128 + (cb ^ xk));
            }
#pragma unroll
            for (int mi = 0; mi < MI; ++mi)
#pragma unroll
                for (int ni = 0; ni < FN; ++ni)
                    acc[mi][ni] = __builtin_amdgcn_mfma_f32_16x16x32_bf16(
                        af[mi], bfr[ni], acc[mi][ni], 0, 0, 0);
        }
        barrier_raw();
    }

    const float* bp = blockIdx.z ? biasB : bias;
    const float al = blockIdx.z ? alphaB : alpha;
#pragma unroll
    for (int mi = 0; mi < MI; ++mi)
#pragma unroll
        for (int ni = 0; ni < FN; ++ni)
#pragma unroll
            for (int r = 0; r < 4; ++r) {
                const int m = m0 + wm * (TM / 2) + mi * 16 + lg * 4 + r;
                const int n = n0 + wn * (TN / 2) + ni * 16 + lm;
                float v = acc[mi][ni][r];
                if constexpr (GATE) v *= gate[(size_t)(m & 511) * 512 + n];
                else                v = (v + bp[n]) * al;
                if constexpr (RELU) v = fmaxf(v, 0.f);
                C[(size_t)m * ldo + n] = f2b(v);
            }
}

// ======== cross scores batched GEMM: SC[b,h] = QW_h @ memb_b^T (f32) ======
// z = b*8+h. QW (B*T,4096) head band h*512; memb (B*S,512). 128x128 tile.
__global__ __launch_bounds__(256) void gemm_scores(
    const u16* __restrict__ QWp, const u16* __restrict__ membp,
    float* __restrict__ SC) {
    __shared__ __align__(16) u16 As[2][128 * 64];
    __shared__ __align__(16) u16 Bs[2][128 * 64];
    const int tid = threadIdx.x;
    const int wave = tid >> 6, lane = tid & 63;
    const int lm = lane & 15, lg = lane >> 4;
    const int wm = wave >> 1, wn = wave & 1;
    const int m0 = blockIdx.y * 128, n0 = blockIdx.x * 128;
    const int z = blockIdx.z, b = z >> 3, h = z & 7;
    const u16* A  = QWp + (size_t)b * TT * 4096 + h * 512;   // lda 4096
    const u16* Bw = membp + (size_t)b * SS * 512;            // ldb 512
    float* C = SC + ((size_t)z << 18);

    f32x4 acc[4][4];
#pragma unroll
    for (int mi = 0; mi < 4; ++mi)
#pragma unroll
        for (int ni = 0; ni < 4; ++ni) acc[mi][ni] = (f32x4){0.f, 0.f, 0.f, 0.f};

    const int srow = lane >> 3;
    const int sbyte = ((lane & 7) << 4) ^ (srow << 4);
    const int xk = (lm & 7) << 4;

    auto stage = [&](int buf, int kt) {
#pragma unroll
        for (int j = 0; j < 4; ++j) {
            const int r = wave * 32 + j * 8;
            g2lds16((const char*)(A + (size_t)(m0 + r + srow) * 4096 + kt) + sbyte,
                    (char*)As[buf] + (size_t)r * 128);
            g2lds16((const char*)(Bw + (size_t)(n0 + r + srow) * 512 + kt) + sbyte,
                    (char*)Bs[buf] + (size_t)r * 128);
        }
    };

    stage(0, 0);
    for (int t = 0; t < 8; ++t) {
        const int cur = t & 1;
        if (t + 1 < 8) { stage(cur ^ 1, (t + 1) << 6); waitvm<8>(); }
        else           { waitvm<0>(); }
        barrier_raw();
#pragma unroll
        for (int kh = 0; kh < 2; ++kh) {
            const int cb = kh * 64 + lg * 16;
            bf16x8 af[4], bfr[4];
#pragma unroll
            for (int mi = 0; mi < 4; ++mi) {
                const int row = wm * 64 + mi * 16 + lm;
                af[mi] = *(const bf16x8*)((const char*)As[cur] + row * 128 + (cb ^ xk));
            }
#pragma unroll
            for (int ni = 0; ni < 4; ++ni) {
                const int row = wn * 64 + ni * 16 + lm;
                bfr[ni] = *(const bf16x8*)((const char*)Bs[cur] + row * 128 + (cb ^ xk));
            }
#pragma unroll
            for (int mi = 0; mi < 4; ++mi)
#pragma unroll
                for (int ni = 0; ni < 4; ++ni)
                    acc[mi][ni] = __builtin_amdgcn_mfma_f32_16x16x32_bf16(
                        af[mi], bfr[ni], acc[mi][ni], 0, 0, 0);
        }
        barrier_raw();
    }
#pragma unroll
    for (int mi = 0; mi < 4; ++mi)
#pragma unroll
        for (int ni = 0; ni < 4; ++ni)
#pragma unroll
            for (int r = 0; r < 4; ++r) {
                const int m = m0 + wm * 64 + mi * 16 + lg * 4 + r;
                const int n = n0 + wn * 64 + ni * 16 + lm;
                C[(size_t)m * 512 + n] = acc[mi][ni][r];
            }
}

// ======== softmax + PV: out[b,t,h*64+] = softmax(SC[b,h,t,:]) @ CV_h ======
// block = (t-tile 64, h, b), 256 thr, 4 waves x 16 t-rows.
// Lane (lm,lg) holds row lm's cols {lg*8+32k+e}: exactly PV A-fragments.
// V^T staged once in 64KB LDS with XOR swizzle (T2).
__global__ __launch_bounds__(256) void softmax_pv(
    const float* __restrict__ SC, const u16* __restrict__ CV,
    u16* __restrict__ out) {
    const int t0 = blockIdx.x * 64, h = blockIdx.y, b = blockIdx.z;
    const int tid = threadIdx.x, wave = tid >> 6, lane = tid & 63;
    const int lm = lane & 15, lg = lane >> 4;
    __shared__ __align__(16) u16 Vt[64 * 512];  // [d][s] swizzled, 64KB

    // ---- stage V^T: thread handles s-pair (2*tid, 2*tid+1) ----
    {
        const int sp = tid * 2;
#pragma unroll
        for (int c = 0; c < 8; ++c) {
            bf16x8 v0 = *(const bf16x8*)(CV + ((size_t)b * SS + sp) * 512 + h * 64 + c * 8);
            bf16x8 v1 = *(const bf16x8*)(CV + ((size_t)b * SS + sp + 1) * 512 + h * 64 + c * 8);
#pragma unroll
            for (int j = 0; j < 8; ++j) {
                const int d = c * 8 + j;
                const unsigned int pk = (unsigned int)(u16)v0[j] |
                                        ((unsigned int)(u16)v1[j] << 16);
                *(unsigned int*)((char*)Vt + ((d << 10) + ((sp * 2) ^ ((d & 7) << 4)))) = pk;
            }
        }
    }

    // ---- load scores (row lm of this wave's 16 rows) ----
    const int tw = t0 + wave * 16;
    const float* srow = SC + ((size_t)(b * 8 + h) << 18) + (size_t)(tw + lm) * 512 + lg * 8;
    float4 sa[16][2];
#pragma unroll
    for (int k = 0; k < 16; ++k) {
        sa[k][0] = *(const float4*)(srow + k * 32);
        sa[k][1] = *(const float4*)(srow + k * 32 + 4);
    }
    // ---- row max (128 local + 2 shfl) ----
    float mx = -3e38f;
#pragma unroll
    for (int k = 0; k < 16; ++k) {
        mx = fmaxf(mx, fmaxf(fmaxf(sa[k][0].x, sa[k][0].y), fmaxf(sa[k][0].z, sa[k][0].w)));
        mx = fmaxf(mx, fmaxf(fmaxf(sa[k][1].x, sa[k][1].y), fmaxf(sa[k][1].z, sa[k][1].w)));
    }
    mx = fmaxf(mx, __shfl_xor(mx, 16));
    mx = fmaxf(mx, __shfl_xor(mx, 32));
    // ---- exp -> bf16 fragments + row sum ----
    float sum = 0.f;
    bf16x8 pb[16];
#pragma unroll
    for (int k = 0; k < 16; ++k) {
        float p0 = __expf(sa[k][0].x - mx), p1 = __expf(sa[k][0].y - mx);
        float p2 = __expf(sa[k][0].z - mx), p3 = __expf(sa[k][0].w - mx);
        float p4 = __expf(sa[k][1].x - mx), p5 = __expf(sa[k][1].y - mx);
        float p6 = __expf(sa[k][1].z - mx), p7 = __expf(sa[k][1].w - mx);
        sum += (p0 + p1 + p2 + p3) + (p4 + p5 + p6 + p7);
        pb[k][0] = (short)f2b(p0); pb[k][1] = (short)f2b(p1);
        pb[k][2] = (short)f2b(p2); pb[k][3] = (short)f2b(p3);
        pb[k][4] = (short)f2b(p4); pb[k][5] = (short)f2b(p5);
        pb[k][6] = (short)f2b(p6); pb[k][7] = (short)f2b(p7);
    }
    sum += __shfl_xor(sum, 16);
    sum += __shfl_xor(sum, 32);

    __syncthreads();  // Vt ready

    // ---- PV: 16 k-chunks x 4 d-frags ----
    f32x4 o[4];
#pragma unroll
    for (int nt = 0; nt < 4; ++nt) o[nt] = (f32x4){0.f, 0.f, 0.f, 0.f};
#pragma unroll
    for (int k = 0; k < 16; ++k) {
#pragma unroll
        for (int nt = 0; nt < 4; ++nt) {
            const int d = nt * 16 + lm;
            const bf16x8 vf = *(const bf16x8*)((const char*)Vt +
                ((d << 10) + ((k * 64 + lg * 16) ^ ((d & 7) << 4))));
            o[nt] = __builtin_amdgcn_mfma_f32_16x16x32_bf16(pb[k], vf, o[nt], 0, 0, 0);
        }
    }
    // ---- divide by row sum (sum lives at lane holding that row as lm) ----
#pragma unroll
    for (int r = 0; r < 4; ++r) {
        const float rs = __shfl(sum, lg * 4 + r);
        const float inv = 1.f / rs;
#pragma unroll
        for (int nt = 0; nt < 4; ++nt)
            out[(size_t)(b * TT + tw + lg * 4 + r) * DD + h * 64 + nt * 16 + lm] =
                f2b(o[nt][r] * inv);
    }
}

// ================= self flash attention (verified r3) =================
__global__ __launch_bounds__(256) void flash_self(const u16* __restrict__ QKV,
                                                  u16* __restrict__ out) {
    const int t0 = blockIdx.x * 64, h = blockIdx.y, b = blockIdx.z;
    const int tid = threadIdx.x, wave = tid >> 6, lane = tid & 63;
    const int lm = lane & 15, lg = lane >> 4;
    __shared__ __align__(16) u16 Ks[32 * 64];
    __shared__ __align__(16) u16 Vt[64][40];
    __shared__ __align__(16) u16 P[4][16][40];

    const int tw = t0 + wave * 16;
    const size_t qrow = (size_t)(b * TT + tw + lm) * 1536 + h * 64;
    bf16x8 qf[2];
    qf[0] = *(const bf16x8*)(QKV + qrow + lg * 8);
    qf[1] = *(const bf16x8*)(QKV + qrow + 32 + lg * 8);

    float m_run[4], l_run[4];
    f32x4 oacc[4];
#pragma unroll
    for (int r = 0; r < 4; ++r) { m_run[r] = -3e38f; l_run[r] = 0.f; }
#pragma unroll
    for (int nt = 0; nt < 4; ++nt) oacc[nt] = (f32x4){0.f, 0.f, 0.f, 0.f};

    const int srow = lane >> 3, sbyte = ((lane & 7) << 4) ^ (srow << 4);
    const int xk = (lm & 7) << 4;
    const int smax = t0 + 64;
    for (int s0 = 0; s0 < smax; s0 += 32) {
        if (s0) __syncthreads();
        g2lds16((const char*)(QKV + (size_t)(b * TT + s0 + wave * 8 + srow) * 1536 +
                              512 + h * 64) + sbyte,
                (char*)Ks + wave * 1024);
        {
            const int s = tid & 31, d0 = (tid >> 5) * 8;
            bf16x8 vv = *(const bf16x8*)(QKV + (size_t)(b * TT + s0 + s) * 1536 +
                                         1024 + h * 64 + d0);
#pragma unroll
            for (int j = 0; j < 8; ++j) Vt[d0 + j][s] = (u16)vv[j];
        }
        __syncthreads();
        if (s0 <= tw + 15) {
            f32x4 sc0 = (f32x4){0.f, 0.f, 0.f, 0.f};
            f32x4 sc1 = (f32x4){0.f, 0.f, 0.f, 0.f};
#pragma unroll
            for (int f = 0; f < 2; ++f) {
                const int cb = f * 64 + lg * 16;
                bf16x8 k0 = *(const bf16x8*)((const char*)Ks + lm * 128 + (cb ^ xk));
                bf16x8 k1 = *(const bf16x8*)((const char*)Ks + (16 + lm) * 128 + (cb ^ xk));
                sc0 = __builtin_amdgcn_mfma_f32_16x16x32_bf16(qf[f], k0, sc0, 0, 0, 0);
                sc1 = __builtin_amdgcn_mfma_f32_16x16x32_bf16(qf[f], k1, sc1, 0, 0, 0);
            }
            float sv0[4], sv1[4], tm[4];
#pragma unroll
            for (int r = 0; r < 4; ++r) {
                const int t = tw + lg * 4 + r;
                sv0[r] = sc0[r] * 0.125f + ((s0 + lm) <= t ? 0.f : -1e9f);
                sv1[r] = sc1[r] * 0.125f + ((s0 + 16 + lm) <= t ? 0.f : -1e9f);
                tm[r] = fmaxf(sv0[r], sv1[r]);
            }
#pragma unroll
            for (int off = 1; off < 16; off <<= 1)
#pragma unroll
                for (int r = 0; r < 4; ++r) tm[r] = fmaxf(tm[r], __shfl_xor(tm[r], off));
            float fac[4], rs[4];
#pragma unroll
            for (int r = 0; r < 4; ++r) {
                const float mn = fmaxf(m_run[r], tm[r]);
                fac[r] = __expf(m_run[r] - mn);
                m_run[r] = mn;
                const float p0 = __expf(sv0[r] - mn);
                const float p1 = __expf(sv1[r] - mn);
                P[wave][lg * 4 + r][lm] = f2b(p0);
                P[wave][lg * 4 + r][16 + lm] = f2b(p1);
                rs[r] = p0 + p1;
            }
#pragma unroll
            for (int off = 1; off < 16; off <<= 1)
#pragma unroll
                for (int r = 0; r < 4; ++r) rs[r] += __shfl_xor(rs[r], off);
#pragma unroll
            for (int r = 0; r < 4; ++r) l_run[r] = l_run[r] * fac[r] + rs[r];
#pragma unroll
            for (int nt = 0; nt < 4; ++nt)
#pragma unroll
                for (int r = 0; r < 4; ++r) oacc[nt][r] *= fac[r];
            const bf16x8 pf = *(const bf16x8*)&P[wave][lm][lg * 8];
#pragma unroll
            for (int nt = 0; nt < 4; ++nt) {
                const bf16x8 vf = *(const bf16x8*)&Vt[nt * 16 + lm][lg * 8];
                oacc[nt] = __builtin_amdgcn_mfma_f32_16x16x32_bf16(pf, vf, oacc[nt], 0, 0, 0);
            }
        }
    }
#pragma unroll
    for (int nt = 0; nt < 4; ++nt)
#pragma unroll
        for (int r = 0; r < 4; ++r)
            out[(size_t)(b * TT + tw + lg * 4 + r) * DD + h * 64 + nt * 16 + lm] =
                f2b(oacc[nt][r] / l_run[r]);
}

// ================= fused residual + LayerNorm =================
template <bool R1B>
__global__ __launch_bounds__(256) void add_ln(
    const void* __restrict__ R1v, const u16* __restrict__ R2,
    const float* __restrict__ g, const float* __restrict__ bta,
    float* __restrict__ outf, u16* __restrict__ outb) {
    const int row = blockIdx.x, tid = threadIdx.x;
    float x0, x1;
    if constexpr (R1B) {
        ushort2 a = ((const ushort2*)((const u16*)R1v + (size_t)row * DD))[tid];
        x0 = b2f(a.x); x1 = b2f(a.y);
    } else {
        float2 a = ((const float2*)((const float*)R1v + (size_t)row * DD))[tid];
        x0 = a.x; x1 = a.y;
    }
    ushort2 c = ((const ushort2*)(R2 + (size_t)row * DD))[tid];
    x0 += b2f(c.x); x1 += b2f(c.y);

    __shared__ float2 red[256];
    red[tid] = make_float2(x0 + x1, x0 * x0 + x1 * x1);
    __syncthreads();
#pragma unroll
    for (int o = 128; o > 0; o >>= 1) {
        if (tid < o) {
            red[tid].x += red[tid + o].x;
            red[tid].y += red[tid + o].y;
        }
        __syncthreads();
    }
    const float mean = red[0].x * (1.f / 512.f);
    const float var = red[0].y * (1.f / 512.f) - mean * mean;
    const float rstd = rsqrtf(var + 1e-5f);
    const int i = tid * 2;
    const float y0 = (x0 - mean) * rstd * g[i] + bta[i];
    const float y1 = (x1 - mean) * rstd * g[i + 1] + bta[i + 1];
    if (outf) ((float2*)(outf + (size_t)row * DD))[tid] = make_float2(y0, y1);
    if (outb) {
        ushort2 ub; ub.x = f2b(y0); ub.y = f2b(y1);
        ((ushort2*)(outb + (size_t)row * DD))[tid] = ub;
    }
}

extern "C" void kernel_launch(void* const* d_in, const int* in_sizes, int n_in,
                              void* d_out, int out_size, void* d_ws, size_t ws_size,
                              hipStream_t stream) {
    const float* tgt      = (const float*)d_in[0];
    const float* memory   = (const float*)d_in[1];
    const float* gate     = (const float*)d_in[3];
    const float* sa_in_w  = (const float*)d_in[4];
    const float* sa_in_b  = (const float*)d_in[5];
    const float* sa_out_w = (const float*)d_in[6];
    const float* sa_out_b = (const float*)d_in[7];
    const float* ca_in_w  = (const float*)d_in[8];
    const float* ca_in_b  = (const float*)d_in[9];
    const float* ca_out_w = (const float*)d_in[10];
    const float* ca_out_b = (const float*)d_in[11];
    const float* ff1_w    = (const float*)d_in[12];
    const float* ff1_b    = (const float*)d_in[13];
    const float* ff2_w    = (const float*)d_in[14];
    const float* ff2_b    = (const float*)d_in[15];
    const float* ln1_g    = (const float*)d_in[16];
    const float* ln1_b    = (const float*)d_in[17];
    const float* ln2_g    = (const float*)d_in[18];
    const float* ln2_b    = (const float*)d_in[19];
    const float* ln3_g    = (const float*)d_in[20];
    const float* ln3_b    = (const float*)d_in[21];

    // ---- workspace layout (u16 units); SC f32 region after tgtb ----
    u16* ws16     = (u16*)d_ws;
    u16* QKVb     = ws16;                    // 6291456
    u16* sa_preb  = ws16 + 6291456;          // 2097152
    u16* PRJb     = ws16 + 8388608;          // 2097152
    u16* X1b      = ws16 + 10485760;         // 2097152
    u16* memb     = ws16 + 12582912;         // 2097152
    u16* CQb      = ws16 + 14680064;         // 2097152
    u16* CVb      = ws16 + 16777216;         // 2097152
    u16* QW       = ws16 + 18874368;         // 16777216 (4096 x 4096)
    u16* ca_preb  = ws16 + 35651584;         // 2097152
    u16* PRJ2b    = ws16 + 37748736;         // 2097152
    u16* X2b      = ws16 + 39845888;         // 2097152
    u16* HHb      = ws16 + 41943040;         // 8388608
    u16* F1b      = ws16 + 50331648;         // 2097152
    u16* Wreg     = ws16 + 52428800;
    u16* sa_in_wb = Wreg;                    // 786432
    u16* sa_out_wb= Wreg + 786432;           // 262144
    u16* ca_wq_b  = Wreg + 1048576;          // 262144
    u16* ca_wv_b  = Wreg + 1310720;          // 262144
    u16* WkT      = Wreg + 1572864;          // 262144
    u16* ca_out_wb= Wreg + 1835008;          // 262144
    u16* ff1_wb   = Wreg + 2097152;          // 1048576
    u16* ff2_wb   = Wreg + 3145728;          // 1048576
    u16* tgtb     = ws16 + 56623104;         // 2097152
    float* SC     = (float*)(ws16 + 58720256);  // 16,777,216 f32 = 67MB
    float* outf   = (float*)d_out;

    const dim3 blk(256);

    // 0. casts
    CastSegs sg;
    sg.s[0]=tgt; sg.s[1]=memory; sg.s[2]=sa_in_w; sg.s[3]=sa_out_w;
    sg.s[4]=ca_in_w; sg.s[5]=ca_in_w + (size_t)1024*512; sg.s[6]=ca_out_w;
    sg.s[7]=ff1_w; sg.s[8]=ff2_w;
    sg.d[0]=tgtb; sg.d[1]=memb; sg.d[2]=sa_in_wb; sg.d[3]=sa_out_wb;
    sg.d[4]=ca_wq_b; sg.d[5]=ca_wv_b; sg.d[6]=ca_out_wb;
    sg.d[7]=ff1_wb; sg.d[8]=ff2_wb;
    {
        const int n4[9] = {524288,524288,196608,65536,65536,65536,65536,262144,262144};
        int c = 0;
        for (int i = 0; i < 9; ++i) { sg.cum[i] = c; c += n4[i]; }
        sg.cum[9] = c;
    }
    cast_multi<<<2048, blk, 0, stream>>>(sg);
    wkt_kernel<<<1024, blk, 0, stream>>>(ca_in_w, WkT);

    // 1. QKV (4096,1536)
    gemm_bf16<128,128,false,false><<<dim3(12,32,1), blk, 0, stream>>>(
        tgtb,512,0, sa_in_wb,512,0, sa_in_b,sa_in_b,nullptr,
        QKVb,1536,0, 512, 1.f,1.f);
    // 2. self flash -> sa_preb
    flash_self<<<dim3(8,8,8), blk, 0, stream>>>(QKVb, sa_preb);
    // 3. proj1
    gemm_bf16<64,64,false,false><<<dim3(8,64,1), blk, 0, stream>>>(
        sa_preb,512,0, sa_out_wb,512,0, sa_out_b,sa_out_b,nullptr,
        PRJb,512,0, 512, 1.f,1.f);
    // 4. LN1 -> X1b
    add_ln<false><<<4096, blk, 0, stream>>>(tgt, PRJb, ln1_g, ln1_b, nullptr, X1b);
    // 5. cq (z=0, alpha .125) + cv (z=1) batched
    gemm_bf16<64,64,false,false><<<dim3(8,64,2), blk, 0, stream>>>(
        X1b,512,2097152, ca_wq_b,512,262144, ca_in_b, ca_in_b+1024, nullptr,
        CQb,512,2097152, 512, 0.125f, 1.f);
    // 6. qWg all heads (z=8, K=64) -> QW (4096,4096)
    gemm_bf16<64,64,false,true><<<dim3(8,64,8), blk, 0, stream>>>(
        CQb,512,64, WkT,64,32768, nullptr,nullptr,gate,
        QW,4096,512, 64, 1.f,1.f);
    // 7a. cross scores (f32) -> SC
    gemm_scores<<<dim3(4,4,64), blk, 0, stream>>>(QW, memb, SC);
    // 7b. softmax + PV -> ca_preb
    softmax_pv<<<dim3(8,8,8), blk, 0, stream>>>(SC, CVb, ca_preb);
    // 8. proj2
    gemm_bf16<64,64,false,false><<<dim3(8,64,1), blk, 0, stream>>>(
        ca_preb,512,0, ca_out_wb,512,0, ca_out_b,ca_out_b,nullptr,
        PRJ2b,512,0, 512, 1.f,1.f);
    // 9. LN2 -> X2b
    add_ln<true><<<4096, blk, 0, stream>>>(X1b, PRJ2b, ln2_g, ln2_b, nullptr, X2b);
    // 10. ff1 + relu -> HHb
    gemm_bf16<128,128,true,false><<<dim3(16,32,1), blk, 0, stream>>>(
        X2b,512,0, ff1_wb,512,0, ff1_b,ff1_b,nullptr,
        HHb,2048,0, 512, 1.f,1.f);
    // 11. ff2 -> F1b
    gemm_bf16<64,64,false,false><<<dim3(8,64,1), blk, 0, stream>>>(
        HHb,2048,0, ff2_wb,2048,0, ff2_b,ff2_b,nullptr,
        F1b,512,0, 2048, 1.f,1.f);
    // 12. LN3 -> d_out
    add_ln<true><<<4096, blk, 0, stream>>>(X2b, F1b, ln3_g, ln3_b, outf, nullptr);

    (void)in_sizes; (void)n_in; (void)out_size; (void)ws_size;
}

// Round 8
// 190.909 us; speedup vs baseline: 1.1897x; 1.1257x over previous
//
#include <hip/hip_runtime.h>
#include <hip/hip_bf16.h>

#define BB 8
#define TT 512
#define SS 512
#define DD 512
#define HH 8

typedef __attribute__((ext_vector_type(8))) short bf16x8;
typedef __attribute__((ext_vector_type(4))) float f32x4;
typedef unsigned short u16;

__device__ __forceinline__ u16 f2b(float f) {
    __hip_bfloat16 h = __float2bfloat16(f);
    return *reinterpret_cast<u16*>(&h);
}
__device__ __forceinline__ float b2f(u16 v) {
    unsigned int u = ((unsigned int)v) << 16;
    return __builtin_bit_cast(float, u);
}
__device__ __forceinline__ void g2lds16(const void* g, void* l) {
    __builtin_amdgcn_global_load_lds(
        (const __attribute__((address_space(1))) void*)g,
        (__attribute__((address_space(3))) void*)l, 16, 0, 0);
}
template <int N> __device__ __forceinline__ void waitvm();
template <> __device__ __forceinline__ void waitvm<0>()  { asm volatile("s_waitcnt vmcnt(0)" ::: "memory"); }
template <> __device__ __forceinline__ void waitvm<4>()  { asm volatile("s_waitcnt vmcnt(4)" ::: "memory"); }
template <> __device__ __forceinline__ void waitvm<6>()  { asm volatile("s_waitcnt vmcnt(6)" ::: "memory"); }
template <> __device__ __forceinline__ void waitvm<8>()  { asm volatile("s_waitcnt vmcnt(8)" ::: "memory"); }
__device__ __forceinline__ void barrier_raw() {
    asm volatile("" ::: "memory");
    __builtin_amdgcn_s_barrier();
    asm volatile("" ::: "memory");
}
// T1: bijective XCD-chunking remap (requires gridDim product % 8 == 0)
__device__ __forceinline__ void xcd_swz(int& bx, int& by, int& bz) {
    const int gx = gridDim.x, gy = gridDim.y, gz = gridDim.z;
    const int n = gx * gy * gz;
    const int flat = bx + gx * (by + gy * bz);
    const int q = n >> 3;
    const int nf = (flat & 7) * q + (flat >> 3);
    bx = nf % gx;
    const int r = nf / gx;
    by = r % gy;
    bz = r / gy;
}

// ========= multi-segment f32 -> bf16 cast (+ fused WkT transpose) =========
struct CastSegs {
    const float* s[9];
    u16* d[9];
    int cum[10];
    const float* wsrc;  // ca_in_w
    u16* wdst;          // WkT
};
__global__ __launch_bounds__(256) void cast_multi(CastSegs sg) {
    const int total = sg.cum[9];
    for (int i = blockIdx.x * 256 + threadIdx.x; i < total; i += gridDim.x * 256) {
        int k = 0;
#pragma unroll
        for (int j = 1; j < 9; ++j) k += (i >= sg.cum[j]);
        const int loc = i - sg.cum[k];
        float4 v = ((const float4*)sg.s[k])[loc];
        ushort4 u;
        u.x = f2b(v.x); u.y = f2b(v.y); u.z = f2b(v.z); u.w = f2b(v.w);
        ((ushort4*)sg.d[k])[loc] = u;
    }
    // WkT[h][d][e] = ca_in_w[(512 + h*64 + e)*512 + d]  (262144 elements)
    for (int idx = blockIdx.x * 256 + threadIdx.x; idx < 262144; idx += gridDim.x * 256) {
        const int h = idx >> 15, d = (idx >> 6) & 511, e = idx & 63;
        sg.wdst[idx] = f2b(sg.wsrc[(size_t)(512 + h * 64 + e) * 512 + d]);
    }
}

// ================= bf16 MFMA GEMM, dbuf prefetch, TM x TN tiles ==========
// C = epi(A(M,K) @ B(N,K)^T). 256 thr (2x2 waves).
template <int TM, int TN, bool RELU, bool GATE, typename OutT = u16, bool ADDBIAS = true>
__global__ __launch_bounds__(256) void gemm_bf16(
    const u16* __restrict__ A, int lda, long az,
    const u16* __restrict__ Bw, int ldb, long bz,
    const float* __restrict__ bias, const float* __restrict__ biasB,
    const float* __restrict__ gate,
    OutT* __restrict__ C, int ldo, long cz,
    int K, float alpha, float alphaB) {
    __shared__ __align__(16) u16 As[2][TM * 64];
    __shared__ __align__(16) u16 Bs[2][TN * 64];
    int bx = blockIdx.x, by = blockIdx.y, bzz = blockIdx.z;
    xcd_swz(bx, by, bzz);
    const int tid = threadIdx.x;
    const int wave = tid >> 6, lane = tid & 63;
    const int lm = lane & 15, lg = lane >> 4;
    const int wm = wave >> 1, wn = wave & 1;
    const int m0 = by * TM, n0 = bx * TN;
    A += (size_t)bzz * az;
    Bw += (size_t)bzz * bz;
    C += (size_t)bzz * cz;
    constexpr int MI = TM / 32;
    constexpr int FN = TN / 32;
    constexpr int LPS = MI + FN;

    f32x4 acc[MI][FN];
#pragma unroll
    for (int mi = 0; mi < MI; ++mi)
#pragma unroll
        for (int ni = 0; ni < FN; ++ni) acc[mi][ni] = (f32x4){0.f, 0.f, 0.f, 0.f};

    const int srow = lane >> 3;
    const int sbyte = ((lane & 7) << 4) ^ (srow << 4);
    const int xk = (lm & 7) << 4;

    auto stage = [&](int buf, int kt) {
#pragma unroll
        for (int j = 0; j < MI; ++j) {
            const int r = wave * (TM / 4) + j * 8;
            g2lds16((const char*)(A + (size_t)(m0 + r + srow) * lda + kt) + sbyte,
                    (char*)As[buf] + (size_t)r * 128);
        }
#pragma unroll
        for (int j = 0; j < FN; ++j) {
            const int r = wave * (TN / 4) + j * 8;
            g2lds16((const char*)(Bw + (size_t)(n0 + r + srow) * ldb + kt) + sbyte,
                    (char*)Bs[buf] + (size_t)r * 128);
        }
    };

    stage(0, 0);
    const int NK = K >> 6;
    for (int t = 0; t < NK; ++t) {
        const int cur = t & 1;
        if (t + 1 < NK) { stage(cur ^ 1, (t + 1) << 6); waitvm<LPS>(); }
        else            { waitvm<0>(); }
        barrier_raw();
#pragma unroll
        for (int kh = 0; kh < 2; ++kh) {
            const int cb = kh * 64 + lg * 16;
            bf16x8 af[MI], bfr[FN];
#pragma unroll
            for (int mi = 0; mi < MI; ++mi) {
                const int row = wm * (TM / 2) + mi * 16 + lm;
                af[mi] = *(const bf16x8*)((const char*)As[cur] + row * 128 + (cb ^ xk));
            }
#pragma unroll
            for (int ni = 0; ni < FN; ++ni) {
                const int row = wn * (TN / 2) + ni * 16 + lm;
                bfr[ni] = *(const bf16x8*)((const char*)Bs[cur] + row * 128 + (cb ^ xk));
            }
#pragma unroll
            for (int mi = 0; mi < MI; ++mi)
#pragma unroll
                for (int ni = 0; ni < FN; ++ni)
                    acc[mi][ni] = __builtin_amdgcn_mfma_f32_16x16x32_bf16(
                        af[mi], bfr[ni], acc[mi][ni], 0, 0, 0);
        }
        barrier_raw();
    }

    const float* bp = bzz ? biasB : bias;
    const float al = bzz ? alphaB : alpha;
#pragma unroll
    for (int mi = 0; mi < MI; ++mi)
#pragma unroll
        for (int ni = 0; ni < FN; ++ni)
#pragma unroll
            for (int r = 0; r < 4; ++r) {
                const int m = m0 + wm * (TM / 2) + mi * 16 + lg * 4 + r;
                const int n = n0 + wn * (TN / 2) + ni * 16 + lm;
                float v = acc[mi][ni][r];
                if constexpr (GATE) v *= gate[(size_t)(m & 511) * 512 + n];
                else if constexpr (ADDBIAS) v = (v + bp[n]) * al;
                if constexpr (RELU) v = fmaxf(v, 0.f);
                if constexpr (sizeof(OutT) == 2) C[(size_t)m * ldo + n] = (OutT)f2b(v);
                else                             C[(size_t)m * ldo + n] = v;
            }
}

// ======== cross scores batched GEMM: SC[b,h] = QW_h @ memb_b^T (f32) ======
__global__ __launch_bounds__(256) void gemm_scores(
    const u16* __restrict__ QWp, const u16* __restrict__ membp,
    float* __restrict__ SC) {
    __shared__ __align__(16) u16 As[2][128 * 64];
    __shared__ __align__(16) u16 Bs[2][128 * 64];
    int bx = blockIdx.x, by = blockIdx.y, bzz = blockIdx.z;
    xcd_swz(bx, by, bzz);
    const int tid = threadIdx.x;
    const int wave = tid >> 6, lane = tid & 63;
    const int lm = lane & 15, lg = lane >> 4;
    const int wm = wave >> 1, wn = wave & 1;
    const int m0 = by * 128, n0 = bx * 128;
    const int z = bzz, b = z >> 3, h = z & 7;
    const u16* A  = QWp + (size_t)b * TT * 4096 + h * 512;   // lda 4096
    const u16* Bw = membp + (size_t)b * SS * 512;            // ldb 512
    float* C = SC + ((size_t)z << 18);

    f32x4 acc[4][4];
#pragma unroll
    for (int mi = 0; mi < 4; ++mi)
#pragma unroll
        for (int ni = 0; ni < 4; ++ni) acc[mi][ni] = (f32x4){0.f, 0.f, 0.f, 0.f};

    const int srow = lane >> 3;
    const int sbyte = ((lane & 7) << 4) ^ (srow << 4);
    const int xk = (lm & 7) << 4;

    auto stage = [&](int buf, int kt) {
#pragma unroll
        for (int j = 0; j < 4; ++j) {
            const int r = wave * 32 + j * 8;
            g2lds16((const char*)(A + (size_t)(m0 + r + srow) * 4096 + kt) + sbyte,
                    (char*)As[buf] + (size_t)r * 128);
            g2lds16((const char*)(Bw + (size_t)(n0 + r + srow) * 512 + kt) + sbyte,
                    (char*)Bs[buf] + (size_t)r * 128);
        }
    };

    stage(0, 0);
    for (int t = 0; t < 8; ++t) {
        const int cur = t & 1;
        if (t + 1 < 8) { stage(cur ^ 1, (t + 1) << 6); waitvm<8>(); }
        else           { waitvm<0>(); }
        barrier_raw();
#pragma unroll
        for (int kh = 0; kh < 2; ++kh) {
            const int cb = kh * 64 + lg * 16;
            bf16x8 af[4], bfr[4];
#pragma unroll
            for (int mi = 0; mi < 4; ++mi) {
                const int row = wm * 64 + mi * 16 + lm;
                af[mi] = *(const bf16x8*)((const char*)As[cur] + row * 128 + (cb ^ xk));
            }
#pragma unroll
            for (int ni = 0; ni < 4; ++ni) {
                const int row = wn * 64 + ni * 16 + lm;
                bfr[ni] = *(const bf16x8*)((const char*)Bs[cur] + row * 128 + (cb ^ xk));
            }
#pragma unroll
            for (int mi = 0; mi < 4; ++mi)
#pragma unroll
                for (int ni = 0; ni < 4; ++ni)
                    acc[mi][ni] = __builtin_amdgcn_mfma_f32_16x16x32_bf16(
                        af[mi], bfr[ni], acc[mi][ni], 0, 0, 0);
        }
        barrier_raw();
    }
#pragma unroll
    for (int mi = 0; mi < 4; ++mi)
#pragma unroll
        for (int ni = 0; ni < 4; ++ni)
#pragma unroll
            for (int r = 0; r < 4; ++r) {
                const int m = m0 + wm * 64 + mi * 16 + lg * 4 + r;
                const int n = n0 + wn * 64 + ni * 16 + lm;
                C[(size_t)m * 512 + n] = acc[mi][ni][r];
            }
}

// ======== softmax + PV: out[b,t,h*64+] = softmax(SC[b,h,t,:]) @ CV_h ======
__global__ __launch_bounds__(256) void softmax_pv(
    const float* __restrict__ SC, const u16* __restrict__ CV,
    u16* __restrict__ out) {
    const int t0 = blockIdx.x * 64, h = blockIdx.y, b = blockIdx.z;
    const int tid = threadIdx.x, wave = tid >> 6, lane = tid & 63;
    const int lm = lane & 15, lg = lane >> 4;
    __shared__ __align__(16) u16 Vt[64 * 512];  // [d][s] swizzled, 64KB

    {
        const int sp = tid * 2;
#pragma unroll
        for (int c = 0; c < 8; ++c) {
            bf16x8 v0 = *(const bf16x8*)(CV + ((size_t)b * SS + sp) * 512 + h * 64 + c * 8);
            bf16x8 v1 = *(const bf16x8*)(CV + ((size_t)b * SS + sp + 1) * 512 + h * 64 + c * 8);
#pragma unroll
            for (int j = 0; j < 8; ++j) {
                const int d = c * 8 + j;
                const unsigned int pk = (unsigned int)(u16)v0[j] |
                                        ((unsigned int)(u16)v1[j] << 16);
                *(unsigned int*)((char*)Vt + ((d << 10) + ((sp * 2) ^ ((d & 7) << 4)))) = pk;
            }
        }
    }

    const int tw = t0 + wave * 16;
    const float* srow = SC + ((size_t)(b * 8 + h) << 18) + (size_t)(tw + lm) * 512 + lg * 8;
    float4 sa[16][2];
#pragma unroll
    for (int k = 0; k < 16; ++k) {
        sa[k][0] = *(const float4*)(srow + k * 32);
        sa[k][1] = *(const float4*)(srow + k * 32 + 4);
    }
    float mx = -3e38f;
#pragma unroll
    for (int k = 0; k < 16; ++k) {
        mx = fmaxf(mx, fmaxf(fmaxf(sa[k][0].x, sa[k][0].y), fmaxf(sa[k][0].z, sa[k][0].w)));
        mx = fmaxf(mx, fmaxf(fmaxf(sa[k][1].x, sa[k][1].y), fmaxf(sa[k][1].z, sa[k][1].w)));
    }
    mx = fmaxf(mx, __shfl_xor(mx, 16));
    mx = fmaxf(mx, __shfl_xor(mx, 32));
    float sum = 0.f;
    bf16x8 pb[16];
#pragma unroll
    for (int k = 0; k < 16; ++k) {
        float p0 = __expf(sa[k][0].x - mx), p1 = __expf(sa[k][0].y - mx);
        float p2 = __expf(sa[k][0].z - mx), p3 = __expf(sa[k][0].w - mx);
        float p4 = __expf(sa[k][1].x - mx), p5 = __expf(sa[k][1].y - mx);
        float p6 = __expf(sa[k][1].z - mx), p7 = __expf(sa[k][1].w - mx);
        sum += (p0 + p1 + p2 + p3) + (p4 + p5 + p6 + p7);
        pb[k][0] = (short)f2b(p0); pb[k][1] = (short)f2b(p1);
        pb[k][2] = (short)f2b(p2); pb[k][3] = (short)f2b(p3);
        pb[k][4] = (short)f2b(p4); pb[k][5] = (short)f2b(p5);
        pb[k][6] = (short)f2b(p6); pb[k][7] = (short)f2b(p7);
    }
    sum += __shfl_xor(sum, 16);
    sum += __shfl_xor(sum, 32);

    __syncthreads();

    f32x4 o[4];
#pragma unroll
    for (int nt = 0; nt < 4; ++nt) o[nt] = (f32x4){0.f, 0.f, 0.f, 0.f};
#pragma unroll
    for (int k = 0; k < 16; ++k) {
#pragma unroll
        for (int nt = 0; nt < 4; ++nt) {
            const int d = nt * 16 + lm;
            const bf16x8 vf = *(const bf16x8*)((const char*)Vt +
                ((d << 10) + ((k * 64 + lg * 16) ^ ((d & 7) << 4))));
            o[nt] = __builtin_amdgcn_mfma_f32_16x16x32_bf16(pb[k], vf, o[nt], 0, 0, 0);
        }
    }
#pragma unroll
    for (int r = 0; r < 4; ++r) {
        const float rs = __shfl(sum, lg * 4 + r);
        const float inv = 1.f / rs;
#pragma unroll
        for (int nt = 0; nt < 4; ++nt)
            out[(size_t)(b * TT + tw + lg * 4 + r) * DD + h * 64 + nt * 16 + lm] =
                f2b(o[nt][r] * inv);
    }
}

// ================= self flash attention (verified r3) =================
__global__ __launch_bounds__(256) void flash_self(const u16* __restrict__ QKV,
                                                  u16* __restrict__ out) {
    const int t0 = blockIdx.x * 64, h = blockIdx.y, b = blockIdx.z;
    const int tid = threadIdx.x, wave = tid >> 6, lane = tid & 63;
    const int lm = lane & 15, lg = lane >> 4;
    __shared__ __align__(16) u16 Ks[32 * 64];
    __shared__ __align__(16) u16 Vt[64][40];
    __shared__ __align__(16) u16 P[4][16][40];

    const int tw = t0 + wave * 16;
    const size_t qrow = (size_t)(b * TT + tw + lm) * 1536 + h * 64;
    bf16x8 qf[2];
    qf[0] = *(const bf16x8*)(QKV + qrow + lg * 8);
    qf[1] = *(const bf16x8*)(QKV + qrow + 32 + lg * 8);

    float m_run[4], l_run[4];
    f32x4 oacc[4];
#pragma unroll
    for (int r = 0; r < 4; ++r) { m_run[r] = -3e38f; l_run[r] = 0.f; }
#pragma unroll
    for (int nt = 0; nt < 4; ++nt) oacc[nt] = (f32x4){0.f, 0.f, 0.f, 0.f};

    const int srow = lane >> 3, sbyte = ((lane & 7) << 4) ^ (srow << 4);
    const int xk = (lm & 7) << 4;
    const int smax = t0 + 64;
    for (int s0 = 0; s0 < smax; s0 += 32) {
        if (s0) __syncthreads();
        g2lds16((const char*)(QKV + (size_t)(b * TT + s0 + wave * 8 + srow) * 1536 +
                              512 + h * 64) + sbyte,
                (char*)Ks + wave * 1024);
        {
            const int s = tid & 31, d0 = (tid >> 5) * 8;
            bf16x8 vv = *(const bf16x8*)(QKV + (size_t)(b * TT + s0 + s) * 1536 +
                                         1024 + h * 64 + d0);
#pragma unroll
            for (int j = 0; j < 8; ++j) Vt[d0 + j][s] = (u16)vv[j];
        }
        __syncthreads();
        if (s0 <= tw + 15) {
            f32x4 sc0 = (f32x4){0.f, 0.f, 0.f, 0.f};
            f32x4 sc1 = (f32x4){0.f, 0.f, 0.f, 0.f};
#pragma unroll
            for (int f = 0; f < 2; ++f) {
                const int cb = f * 64 + lg * 16;
                bf16x8 k0 = *(const bf16x8*)((const char*)Ks + lm * 128 + (cb ^ xk));
                bf16x8 k1 = *(const bf16x8*)((const char*)Ks + (16 + lm) * 128 + (cb ^ xk));
                sc0 = __builtin_amdgcn_mfma_f32_16x16x32_bf16(qf[f], k0, sc0, 0, 0, 0);
                sc1 = __builtin_amdgcn_mfma_f32_16x16x32_bf16(qf[f], k1, sc1, 0, 0, 0);
            }
            float sv0[4], sv1[4], tm[4];
#pragma unroll
            for (int r = 0; r < 4; ++r) {
                const int t = tw + lg * 4 + r;
                sv0[r] = sc0[r] * 0.125f + ((s0 + lm) <= t ? 0.f : -1e9f);
                sv1[r] = sc1[r] * 0.125f + ((s0 + 16 + lm) <= t ? 0.f : -1e9f);
                tm[r] = fmaxf(sv0[r], sv1[r]);
            }
#pragma unroll
            for (int off = 1; off < 16; off <<= 1)
#pragma unroll
                for (int r = 0; r < 4; ++r) tm[r] = fmaxf(tm[r], __shfl_xor(tm[r], off));
            float fac[4], rs[4];
#pragma unroll
            for (int r = 0; r < 4; ++r) {
                const float mn = fmaxf(m_run[r], tm[r]);
                fac[r] = __expf(m_run[r] - mn);
                m_run[r] = mn;
                const float p0 = __expf(sv0[r] - mn);
                const float p1 = __expf(sv1[r] - mn);
                P[wave][lg * 4 + r][lm] = f2b(p0);
                P[wave][lg * 4 + r][16 + lm] = f2b(p1);
                rs[r] = p0 + p1;
            }
#pragma unroll
            for (int off = 1; off < 16; off <<= 1)
#pragma unroll
                for (int r = 0; r < 4; ++r) rs[r] += __shfl_xor(rs[r], off);
#pragma unroll
            for (int r = 0; r < 4; ++r) l_run[r] = l_run[r] * fac[r] + rs[r];
#pragma unroll
            for (int nt = 0; nt < 4; ++nt)
#pragma unroll
                for (int r = 0; r < 4; ++r) oacc[nt][r] *= fac[r];
            const bf16x8 pf = *(const bf16x8*)&P[wave][lm][lg * 8];
#pragma unroll
            for (int nt = 0; nt < 4; ++nt) {
                const bf16x8 vf = *(const bf16x8*)&Vt[nt * 16 + lm][lg * 8];
                oacc[nt] = __builtin_amdgcn_mfma_f32_16x16x32_bf16(pf, vf, oacc[nt], 0, 0, 0);
            }
        }
    }
#pragma unroll
    for (int nt = 0; nt < 4; ++nt)
#pragma unroll
        for (int r = 0; r < 4; ++r)
            out[(size_t)(b * TT + tw + lg * 4 + r) * DD + h * 64 + nt * 16 + lm] =
                f2b(oacc[nt][r] / l_run[r]);
}

// ================= fused residual + LayerNorm =================
template <bool R1B>
__global__ __launch_bounds__(256) void add_ln(
    const void* __restrict__ R1v, const u16* __restrict__ R2,
    const float* __restrict__ g, const float* __restrict__ bta,
    float* __restrict__ outf, u16* __restrict__ outb) {
    const int row = blockIdx.x, tid = threadIdx.x;
    float x0, x1;
    if constexpr (R1B) {
        ushort2 a = ((const ushort2*)((const u16*)R1v + (size_t)row * DD))[tid];
        x0 = b2f(a.x); x1 = b2f(a.y);
    } else {
        float2 a = ((const float2*)((const float*)R1v + (size_t)row * DD))[tid];
        x0 = a.x; x1 = a.y;
    }
    ushort2 c = ((const ushort2*)(R2 + (size_t)row * DD))[tid];
    x0 += b2f(c.x); x1 += b2f(c.y);

    __shared__ float2 red[256];
    red[tid] = make_float2(x0 + x1, x0 * x0 + x1 * x1);
    __syncthreads();
#pragma unroll
    for (int o = 128; o > 0; o >>= 1) {
        if (tid < o) {
            red[tid].x += red[tid + o].x;
            red[tid].y += red[tid + o].y;
        }
        __syncthreads();
    }
    const float mean = red[0].x * (1.f / 512.f);
    const float var = red[0].y * (1.f / 512.f) - mean * mean;
    const float rstd = rsqrtf(var + 1e-5f);
    const int i = tid * 2;
    const float y0 = (x0 - mean) * rstd * g[i] + bta[i];
    const float y1 = (x1 - mean) * rstd * g[i + 1] + bta[i + 1];
    if (outf) ((float2*)(outf + (size_t)row * DD))[tid] = make_float2(y0, y1);
    if (outb) {
        ushort2 ub; ub.x = f2b(y0); ub.y = f2b(y1);
        ((ushort2*)(outb + (size_t)row * DD))[tid] = ub;
    }
}

// ==== LN3 with fused split-K reduce: x = X2 + (P0 + P1 + bias) ====
__global__ __launch_bounds__(256) void add_ln_sk(
    const u16* __restrict__ X2, const float* __restrict__ P0,
    const float* __restrict__ P1, const float* __restrict__ fb,
    const float* __restrict__ g, const float* __restrict__ bta,
    float* __restrict__ outf) {
    const int row = blockIdx.x, tid = threadIdx.x;
    ushort2 a = ((const ushort2*)(X2 + (size_t)row * DD))[tid];
    float2 p0 = ((const float2*)(P0 + (size_t)row * DD))[tid];
    float2 p1 = ((const float2*)(P1 + (size_t)row * DD))[tid];
    const int i = tid * 2;
    float x0 = b2f(a.x) + p0.x + p1.x + fb[i];
    float x1 = b2f(a.y) + p0.y + p1.y + fb[i + 1];

    __shared__ float2 red[256];
    red[tid] = make_float2(x0 + x1, x0 * x0 + x1 * x1);
    __syncthreads();
#pragma unroll
    for (int o = 128; o > 0; o >>= 1) {
        if (tid < o) {
            red[tid].x += red[tid + o].x;
            red[tid].y += red[tid + o].y;
        }
        __syncthreads();
    }
    const float mean = red[0].x * (1.f / 512.f);
    const float var = red[0].y * (1.f / 512.f) - mean * mean;
    const float rstd = rsqrtf(var + 1e-5f);
    const float y0 = (x0 - mean) * rstd * g[i] + bta[i];
    const float y1 = (x1 - mean) * rstd * g[i + 1] + bta[i + 1];
    ((float2*)(outf + (size_t)row * DD))[tid] = make_float2(y0, y1);
}

extern "C" void kernel_launch(void* const* d_in, const int* in_sizes, int n_in,
                              void* d_out, int out_size, void* d_ws, size_t ws_size,
                              hipStream_t stream) {
    const float* tgt      = (const float*)d_in[0];
    const float* memory   = (const float*)d_in[1];
    const float* gate     = (const float*)d_in[3];
    const float* sa_in_w  = (const float*)d_in[4];
    const float* sa_in_b  = (const float*)d_in[5];
    const float* sa_out_w = (const float*)d_in[6];
    const float* sa_out_b = (const float*)d_in[7];
    const float* ca_in_w  = (const float*)d_in[8];
    const float* ca_in_b  = (const float*)d_in[9];
    const float* ca_out_w = (const float*)d_in[10];
    const float* ca_out_b = (const float*)d_in[11];
    const float* ff1_w    = (const float*)d_in[12];
    const float* ff1_b    = (const float*)d_in[13];
    const float* ff2_w    = (const float*)d_in[14];
    const float* ff2_b    = (const float*)d_in[15];
    const float* ln1_g    = (const float*)d_in[16];
    const float* ln1_b    = (const float*)d_in[17];
    const float* ln2_g    = (const float*)d_in[18];
    const float* ln2_b    = (const float*)d_in[19];
    const float* ln3_g    = (const float*)d_in[20];
    const float* ln3_b    = (const float*)d_in[21];

    // ---- workspace layout (u16 units) ----
    u16* ws16     = (u16*)d_ws;
    u16* QKVb     = ws16;                    // 6291456
    u16* sa_preb  = ws16 + 6291456;          // 2097152
    u16* PRJb     = ws16 + 8388608;          // 2097152
    u16* X1b      = ws16 + 10485760;         // 2097152
    u16* memb     = ws16 + 12582912;         // 2097152
    u16* CQb      = ws16 + 14680064;         // 2097152
    u16* CVb      = ws16 + 16777216;         // 2097152
    u16* QW       = ws16 + 18874368;         // 16777216 (4096 x 4096)
    u16* ca_preb  = ws16 + 35651584;         // 2097152
    u16* PRJ2b    = ws16 + 37748736;         // 2097152
    u16* X2b      = ws16 + 39845888;         // 2097152
    u16* HHb      = ws16 + 41943040;         // 8388608
    u16* Wreg     = ws16 + 52428800;
    u16* sa_in_wb = Wreg;                    // 786432
    u16* sa_out_wb= Wreg + 786432;           // 262144
    u16* ca_wq_b  = Wreg + 1048576;          // 262144
    u16* ca_wv_b  = Wreg + 1310720;          // 262144
    u16* WkT      = Wreg + 1572864;          // 262144
    u16* ca_out_wb= Wreg + 1835008;          // 262144
    u16* ff1_wb   = Wreg + 2097152;          // 1048576
    u16* ff2_wb   = Wreg + 3145728;          // 1048576
    u16* tgtb     = ws16 + 56623104;         // 2097152
    float* SC     = (float*)(ws16 + 58720256);  // 16,777,216 f32 (cross scores / ff2 partials)
    float* outf   = (float*)d_out;

    const dim3 blk(256);

    // 0. casts (+ fused WkT transpose)
    CastSegs sg;
    sg.s[0]=tgt; sg.s[1]=memory; sg.s[2]=sa_in_w; sg.s[3]=sa_out_w;
    sg.s[4]=ca_in_w; sg.s[5]=ca_in_w + (size_t)1024*512; sg.s[6]=ca_out_w;
    sg.s[7]=ff1_w; sg.s[8]=ff2_w;
    sg.d[0]=tgtb; sg.d[1]=memb; sg.d[2]=sa_in_wb; sg.d[3]=sa_out_wb;
    sg.d[4]=ca_wq_b; sg.d[5]=ca_wv_b; sg.d[6]=ca_out_wb;
    sg.d[7]=ff1_wb; sg.d[8]=ff2_wb;
    sg.wsrc = ca_in_w; sg.wdst = WkT;
    {
        const int n4[9] = {524288,524288,196608,65536,65536,65536,65536,262144,262144};
        int c = 0;
        for (int i = 0; i < 9; ++i) { sg.cum[i] = c; c += n4[i]; }
        sg.cum[9] = c;
    }
    cast_multi<<<2048, blk, 0, stream>>>(sg);

    // 1. QKV (4096,1536)
    gemm_bf16<128,128,false,false><<<dim3(12,32,1), blk, 0, stream>>>(
        tgtb,512,0, sa_in_wb,512,0, sa_in_b,sa_in_b,nullptr,
        QKVb,1536,0, 512, 1.f,1.f);
    // 2. self flash -> sa_preb
    flash_self<<<dim3(8,8,8), blk, 0, stream>>>(QKVb, sa_preb);
    // 3. proj1
    gemm_bf16<64,64,false,false><<<dim3(8,64,1), blk, 0, stream>>>(
        sa_preb,512,0, sa_out_wb,512,0, sa_out_b,sa_out_b,nullptr,
        PRJb,512,0, 512, 1.f,1.f);
    // 4. LN1 -> X1b
    add_ln<false><<<4096, blk, 0, stream>>>(tgt, PRJb, ln1_g, ln1_b, nullptr, X1b);
    // 5. cq (z=0, alpha .125) + cv (z=1) batched
    gemm_bf16<64,64,false,false><<<dim3(8,64,2), blk, 0, stream>>>(
        X1b,512,2097152, ca_wq_b,512,262144, ca_in_b, ca_in_b+1024, nullptr,
        CQb,512,2097152, 512, 0.125f, 1.f);
    // 6. qWg all heads (z=8, K=64) -> QW (4096,4096)
    gemm_bf16<64,64,false,true><<<dim3(8,64,8), blk, 0, stream>>>(
        CQb,512,64, WkT,64,32768, nullptr,nullptr,gate,
        QW,4096,512, 64, 1.f,1.f);
    // 7a. cross scores (f32) -> SC
    gemm_scores<<<dim3(4,4,64), blk, 0, stream>>>(QW, memb, SC);
    // 7b. softmax + PV -> ca_preb
    softmax_pv<<<dim3(8,8,8), blk, 0, stream>>>(SC, CVb, ca_preb);
    // 8. proj2
    gemm_bf16<64,64,false,false><<<dim3(8,64,1), blk, 0, stream>>>(
        ca_preb,512,0, ca_out_wb,512,0, ca_out_b,ca_out_b,nullptr,
        PRJ2b,512,0, 512, 1.f,1.f);
    // 9. LN2 -> X2b
    add_ln<true><<<4096, blk, 0, stream>>>(X1b, PRJ2b, ln2_g, ln2_b, nullptr, X2b);
    // 10. ff1 + relu -> HHb
    gemm_bf16<128,128,true,false><<<dim3(16,32,1), blk, 0, stream>>>(
        X2b,512,0, ff1_wb,512,0, ff1_b,ff1_b,nullptr,
        HHb,2048,0, 512, 1.f,1.f);
    // 11. ff2 split-K=2: z selects K-half (A,B column offset 1024); f32 partials
    gemm_bf16<64,64,false,false,float,false><<<dim3(8,64,2), blk, 0, stream>>>(
        HHb,2048,1024, ff2_wb,2048,1024, nullptr,nullptr,nullptr,
        SC,512,2097152, 1024, 1.f,1.f);
    // 12. LN3 with fused reduce + bias -> d_out
    add_ln_sk<<<4096, blk, 0, stream>>>(X2b, SC, SC + 2097152, ff2_b,
                                        ln3_g, ln3_b, outf);

    (void)in_sizes; (void)n_in; (void)out_size; (void)ws_size;
}

// Round 9
// 184.645 us; speedup vs baseline: 1.2300x; 1.0339x over previous
//
#include <hip/hip_runtime.h>
#include <hip/hip_bf16.h>

#define BB 8
#define TT 512
#define SS 512
#define DD 512
#define HH 8

typedef __attribute__((ext_vector_type(8))) short bf16x8;
typedef __attribute__((ext_vector_type(4))) float f32x4;
typedef unsigned short u16;

__device__ __forceinline__ u16 f2b(float f) {
    __hip_bfloat16 h = __float2bfloat16(f);
    return *reinterpret_cast<u16*>(&h);
}
__device__ __forceinline__ float b2f(u16 v) {
    unsigned int u = ((unsigned int)v) << 16;
    return __builtin_bit_cast(float, u);
}
__device__ __forceinline__ void g2lds16(const void* g, void* l) {
    __builtin_amdgcn_global_load_lds(
        (const __attribute__((address_space(1))) void*)g,
        (__attribute__((address_space(3))) void*)l, 16, 0, 0);
}
template <int N> __device__ __forceinline__ void waitvm();
template <> __device__ __forceinline__ void waitvm<0>()  { asm volatile("s_waitcnt vmcnt(0)" ::: "memory"); }
template <> __device__ __forceinline__ void waitvm<4>()  { asm volatile("s_waitcnt vmcnt(4)" ::: "memory"); }
template <> __device__ __forceinline__ void waitvm<6>()  { asm volatile("s_waitcnt vmcnt(6)" ::: "memory"); }
template <> __device__ __forceinline__ void waitvm<8>()  { asm volatile("s_waitcnt vmcnt(8)" ::: "memory"); }
__device__ __forceinline__ void barrier_raw() {
    asm volatile("" ::: "memory");
    __builtin_amdgcn_s_barrier();
    asm volatile("" ::: "memory");
}
// T1: bijective XCD-chunking remap (requires gridDim product % 8 == 0)
__device__ __forceinline__ void xcd_swz(int& bx, int& by, int& bz) {
    const int gx = gridDim.x, gy = gridDim.y, gz = gridDim.z;
    const int n = gx * gy * gz;
    const int flat = bx + gx * (by + gy * bz);
    const int q = n >> 3;
    const int nf = (flat & 7) * q + (flat >> 3);
    bx = nf % gx;
    const int r = nf / gx;
    by = r % gy;
    bz = r / gy;
}

// ========= multi-segment f32 -> bf16 cast (+ fused WkT transpose) =========
struct CastSegs {
    const float* s[9];
    u16* d[9];
    int cum[10];
    const float* wsrc;  // ca_in_w
    u16* wdst;          // WkT
};
__global__ __launch_bounds__(256) void cast_multi(CastSegs sg) {
    const int total = sg.cum[9];
    for (int i = blockIdx.x * 256 + threadIdx.x; i < total; i += gridDim.x * 256) {
        int k = 0;
#pragma unroll
        for (int j = 1; j < 9; ++j) k += (i >= sg.cum[j]);
        const int loc = i - sg.cum[k];
        float4 v = ((const float4*)sg.s[k])[loc];
        ushort4 u;
        u.x = f2b(v.x); u.y = f2b(v.y); u.z = f2b(v.z); u.w = f2b(v.w);
        ((ushort4*)sg.d[k])[loc] = u;
    }
    // WkT[h][d][e] = ca_in_w[(512 + h*64 + e)*512 + d]  (262144 elements)
    for (int idx = blockIdx.x * 256 + threadIdx.x; idx < 262144; idx += gridDim.x * 256) {
        const int h = idx >> 15, d = (idx >> 6) & 511, e = idx & 63;
        sg.wdst[idx] = f2b(sg.wsrc[(size_t)(512 + h * 64 + e) * 512 + d]);
    }
}

// ================= bf16 MFMA GEMM, dbuf prefetch, TM x TN tiles ==========
// C = epi(A(M,K) @ B(N,K)^T). 256 thr (2x2 waves).
template <int TM, int TN, bool RELU, bool GATE, typename OutT = u16, bool ADDBIAS = true>
__global__ __launch_bounds__(256) void gemm_bf16(
    const u16* __restrict__ A, int lda, long az,
    const u16* __restrict__ Bw, int ldb, long bz,
    const float* __restrict__ bias, const float* __restrict__ biasB,
    const float* __restrict__ gate,
    OutT* __restrict__ C, int ldo, long cz,
    int K, float alpha, float alphaB) {
    __shared__ __align__(16) u16 As[2][TM * 64];
    __shared__ __align__(16) u16 Bs[2][TN * 64];
    int bx = blockIdx.x, by = blockIdx.y, bzz = blockIdx.z;
    xcd_swz(bx, by, bzz);
    const int tid = threadIdx.x;
    const int wave = tid >> 6, lane = tid & 63;
    const int lm = lane & 15, lg = lane >> 4;
    const int wm = wave >> 1, wn = wave & 1;
    const int m0 = by * TM, n0 = bx * TN;
    A += (size_t)bzz * az;
    Bw += (size_t)bzz * bz;
    C += (size_t)bzz * cz;
    constexpr int MI = TM / 32;
    constexpr int FN = TN / 32;
    constexpr int LPS = MI + FN;

    f32x4 acc[MI][FN];
#pragma unroll
    for (int mi = 0; mi < MI; ++mi)
#pragma unroll
        for (int ni = 0; ni < FN; ++ni) acc[mi][ni] = (f32x4){0.f, 0.f, 0.f, 0.f};

    const int srow = lane >> 3;
    const int sbyte = ((lane & 7) << 4) ^ (srow << 4);
    const int xk = (lm & 7) << 4;

    auto stage = [&](int buf, int kt) {
#pragma unroll
        for (int j = 0; j < MI; ++j) {
            const int r = wave * (TM / 4) + j * 8;
            g2lds16((const char*)(A + (size_t)(m0 + r + srow) * lda + kt) + sbyte,
                    (char*)As[buf] + (size_t)r * 128);
        }
#pragma unroll
        for (int j = 0; j < FN; ++j) {
            const int r = wave * (TN / 4) + j * 8;
            g2lds16((const char*)(Bw + (size_t)(n0 + r + srow) * ldb + kt) + sbyte,
                    (char*)Bs[buf] + (size_t)r * 128);
        }
    };

    stage(0, 0);
    const int NK = K >> 6;
    for (int t = 0; t < NK; ++t) {
        const int cur = t & 1;
        if (t + 1 < NK) { stage(cur ^ 1, (t + 1) << 6); waitvm<LPS>(); }
        else            { waitvm<0>(); }
        barrier_raw();
#pragma unroll
        for (int kh = 0; kh < 2; ++kh) {
            const int cb = kh * 64 + lg * 16;
            bf16x8 af[MI], bfr[FN];
#pragma unroll
            for (int mi = 0; mi < MI; ++mi) {
                const int row = wm * (TM / 2) + mi * 16 + lm;
                af[mi] = *(const bf16x8*)((const char*)As[cur] + row * 128 + (cb ^ xk));
            }
#pragma unroll
            for (int ni = 0; ni < FN; ++ni) {
                const int row = wn * (TN / 2) + ni * 16 + lm;
                bfr[ni] = *(const bf16x8*)((const char*)Bs[cur] + row * 128 + (cb ^ xk));
            }
#pragma unroll
            for (int mi = 0; mi < MI; ++mi)
#pragma unroll
                for (int ni = 0; ni < FN; ++ni)
                    acc[mi][ni] = __builtin_amdgcn_mfma_f32_16x16x32_bf16(
                        af[mi], bfr[ni], acc[mi][ni], 0, 0, 0);
        }
        barrier_raw();
    }

    const float* bp = bzz ? biasB : bias;
    const float al = bzz ? alphaB : alpha;
#pragma unroll
    for (int mi = 0; mi < MI; ++mi)
#pragma unroll
        for (int ni = 0; ni < FN; ++ni)
#pragma unroll
            for (int r = 0; r < 4; ++r) {
                const int m = m0 + wm * (TM / 2) + mi * 16 + lg * 4 + r;
                const int n = n0 + wn * (TN / 2) + ni * 16 + lm;
                float v = acc[mi][ni][r];
                if constexpr (GATE) v *= gate[(size_t)(m & 511) * 512 + n];
                else if constexpr (ADDBIAS) v = (v + bp[n]) * al;
                if constexpr (RELU) v = fmaxf(v, 0.f);
                if constexpr (sizeof(OutT) == 2) C[(size_t)m * ldo + n] = (OutT)f2b(v);
                else                             C[(size_t)m * ldo + n] = v;
            }
}

// ======== cross scores batched GEMM: SC[b,h] = QW_h @ memb_b^T (bf16) ====
__global__ __launch_bounds__(256) void gemm_scores(
    const u16* __restrict__ QWp, const u16* __restrict__ membp,
    u16* __restrict__ SC) {
    __shared__ __align__(16) u16 As[2][128 * 64];
    __shared__ __align__(16) u16 Bs[2][128 * 64];
    int bx = blockIdx.x, by = blockIdx.y, bzz = blockIdx.z;
    xcd_swz(bx, by, bzz);
    const int tid = threadIdx.x;
    const int wave = tid >> 6, lane = tid & 63;
    const int lm = lane & 15, lg = lane >> 4;
    const int wm = wave >> 1, wn = wave & 1;
    const int m0 = by * 128, n0 = bx * 128;
    const int z = bzz, b = z >> 3, h = z & 7;
    const u16* A  = QWp + (size_t)b * TT * 4096 + h * 512;   // lda 4096
    const u16* Bw = membp + (size_t)b * SS * 512;            // ldb 512
    u16* C = SC + ((size_t)z << 18);

    f32x4 acc[4][4];
#pragma unroll
    for (int mi = 0; mi < 4; ++mi)
#pragma unroll
        for (int ni = 0; ni < 4; ++ni) acc[mi][ni] = (f32x4){0.f, 0.f, 0.f, 0.f};

    const int srow = lane >> 3;
    const int sbyte = ((lane & 7) << 4) ^ (srow << 4);
    const int xk = (lm & 7) << 4;

    auto stage = [&](int buf, int kt) {
#pragma unroll
        for (int j = 0; j < 4; ++j) {
            const int r = wave * 32 + j * 8;
            g2lds16((const char*)(A + (size_t)(m0 + r + srow) * 4096 + kt) + sbyte,
                    (char*)As[buf] + (size_t)r * 128);
            g2lds16((const char*)(Bw + (size_t)(n0 + r + srow) * 512 + kt) + sbyte,
                    (char*)Bs[buf] + (size_t)r * 128);
        }
    };

    stage(0, 0);
    for (int t = 0; t < 8; ++t) {
        const int cur = t & 1;
        if (t + 1 < 8) { stage(cur ^ 1, (t + 1) << 6); waitvm<8>(); }
        else           { waitvm<0>(); }
        barrier_raw();
#pragma unroll
        for (int kh = 0; kh < 2; ++kh) {
            const int cb = kh * 64 + lg * 16;
            bf16x8 af[4], bfr[4];
#pragma unroll
            for (int mi = 0; mi < 4; ++mi) {
                const int row = wm * 64 + mi * 16 + lm;
                af[mi] = *(const bf16x8*)((const char*)As[cur] + row * 128 + (cb ^ xk));
            }
#pragma unroll
            for (int ni = 0; ni < 4; ++ni) {
                const int row = wn * 64 + ni * 16 + lm;
                bfr[ni] = *(const bf16x8*)((const char*)Bs[cur] + row * 128 + (cb ^ xk));
            }
#pragma unroll
            for (int mi = 0; mi < 4; ++mi)
#pragma unroll
                for (int ni = 0; ni < 4; ++ni)
                    acc[mi][ni] = __builtin_amdgcn_mfma_f32_16x16x32_bf16(
                        af[mi], bfr[ni], acc[mi][ni], 0, 0, 0);
        }
        barrier_raw();
    }
#pragma unroll
    for (int mi = 0; mi < 4; ++mi)
#pragma unroll
        for (int ni = 0; ni < 4; ++ni)
#pragma unroll
            for (int r = 0; r < 4; ++r) {
                const int m = m0 + wm * 64 + mi * 16 + lg * 4 + r;
                const int n = n0 + wn * 64 + ni * 16 + lm;
                C[(size_t)m * 512 + n] = f2b(acc[mi][ni][r]);
            }
}

// ======== softmax + PV: out[b,t,h*64+] = softmax(SC[b,h,t,:]) @ CV_h ======
// SC is bf16. Lane (lm,lg) holds row lm's cols {lg*8+32k+e}: PV A-fragments.
__global__ __launch_bounds__(256) void softmax_pv(
    const u16* __restrict__ SC, const u16* __restrict__ CV,
    u16* __restrict__ out) {
    const int t0 = blockIdx.x * 64, h = blockIdx.y, b = blockIdx.z;
    const int tid = threadIdx.x, wave = tid >> 6, lane = tid & 63;
    const int lm = lane & 15, lg = lane >> 4;
    __shared__ __align__(16) u16 Vt[64 * 512];  // [d][s] swizzled, 64KB

    {
        const int sp = tid * 2;
#pragma unroll
        for (int c = 0; c < 8; ++c) {
            bf16x8 v0 = *(const bf16x8*)(CV + ((size_t)b * SS + sp) * 512 + h * 64 + c * 8);
            bf16x8 v1 = *(const bf16x8*)(CV + ((size_t)b * SS + sp + 1) * 512 + h * 64 + c * 8);
#pragma unroll
            for (int j = 0; j < 8; ++j) {
                const int d = c * 8 + j;
                const unsigned int pk = (unsigned int)(u16)v0[j] |
                                        ((unsigned int)(u16)v1[j] << 16);
                *(unsigned int*)((char*)Vt + ((d << 10) + ((sp * 2) ^ ((d & 7) << 4)))) = pk;
            }
        }
    }

    const int tw = t0 + wave * 16;
    const u16* srow = SC + ((size_t)(b * 8 + h) << 18) + (size_t)(tw + lm) * 512 + lg * 8;
    float sa[16][8];
#pragma unroll
    for (int k = 0; k < 16; ++k) {
        const bf16x8 sv = *(const bf16x8*)(srow + k * 32);
#pragma unroll
        for (int j = 0; j < 8; ++j) sa[k][j] = b2f((u16)sv[j]);
    }
    float mx = -3e38f;
#pragma unroll
    for (int k = 0; k < 16; ++k)
#pragma unroll
        for (int j = 0; j < 8; ++j) mx = fmaxf(mx, sa[k][j]);
    mx = fmaxf(mx, __shfl_xor(mx, 16));
    mx = fmaxf(mx, __shfl_xor(mx, 32));
    float sum = 0.f;
    bf16x8 pb[16];
#pragma unroll
    for (int k = 0; k < 16; ++k) {
#pragma unroll
        for (int j = 0; j < 8; ++j) {
            const float p = __expf(sa[k][j] - mx);
            sum += p;
            pb[k][j] = (short)f2b(p);
        }
    }
    sum += __shfl_xor(sum, 16);
    sum += __shfl_xor(sum, 32);

    __syncthreads();

    f32x4 o[4];
#pragma unroll
    for (int nt = 0; nt < 4; ++nt) o[nt] = (f32x4){0.f, 0.f, 0.f, 0.f};
#pragma unroll
    for (int k = 0; k < 16; ++k) {
#pragma unroll
        for (int nt = 0; nt < 4; ++nt) {
            const int d = nt * 16 + lm;
            const bf16x8 vf = *(const bf16x8*)((const char*)Vt +
                ((d << 10) + ((k * 64 + lg * 16) ^ ((d & 7) << 4))));
            o[nt] = __builtin_amdgcn_mfma_f32_16x16x32_bf16(pb[k], vf, o[nt], 0, 0, 0);
        }
    }
#pragma unroll
    for (int r = 0; r < 4; ++r) {
        const float rs = __shfl(sum, lg * 4 + r);
        const float inv = 1.f / rs;
#pragma unroll
        for (int nt = 0; nt < 4; ++nt)
            out[(size_t)(b * TT + tw + lg * 4 + r) * DD + h * 64 + nt * 16 + lm] =
                f2b(o[nt][r] * inv);
    }
}

// ================= self flash attention (verified r3) =================
__global__ __launch_bounds__(256) void flash_self(const u16* __restrict__ QKV,
                                                  u16* __restrict__ out) {
    const int t0 = blockIdx.x * 64, h = blockIdx.y, b = blockIdx.z;
    const int tid = threadIdx.x, wave = tid >> 6, lane = tid & 63;
    const int lm = lane & 15, lg = lane >> 4;
    __shared__ __align__(16) u16 Ks[32 * 64];
    __shared__ __align__(16) u16 Vt[64][40];
    __shared__ __align__(16) u16 P[4][16][40];

    const int tw = t0 + wave * 16;
    const size_t qrow = (size_t)(b * TT + tw + lm) * 1536 + h * 64;
    bf16x8 qf[2];
    qf[0] = *(const bf16x8*)(QKV + qrow + lg * 8);
    qf[1] = *(const bf16x8*)(QKV + qrow + 32 + lg * 8);

    float m_run[4], l_run[4];
    f32x4 oacc[4];
#pragma unroll
    for (int r = 0; r < 4; ++r) { m_run[r] = -3e38f; l_run[r] = 0.f; }
#pragma unroll
    for (int nt = 0; nt < 4; ++nt) oacc[nt] = (f32x4){0.f, 0.f, 0.f, 0.f};

    const int srow = lane >> 3, sbyte = ((lane & 7) << 4) ^ (srow << 4);
    const int xk = (lm & 7) << 4;
    const int smax = t0 + 64;
    for (int s0 = 0; s0 < smax; s0 += 32) {
        if (s0) __syncthreads();
        g2lds16((const char*)(QKV + (size_t)(b * TT + s0 + wave * 8 + srow) * 1536 +
                              512 + h * 64) + sbyte,
                (char*)Ks + wave * 1024);
        {
            const int s = tid & 31, d0 = (tid >> 5) * 8;
            bf16x8 vv = *(const bf16x8*)(QKV + (size_t)(b * TT + s0 + s) * 1536 +
                                         1024 + h * 64 + d0);
#pragma unroll
            for (int j = 0; j < 8; ++j) Vt[d0 + j][s] = (u16)vv[j];
        }
        __syncthreads();
        if (s0 <= tw + 15) {
            f32x4 sc0 = (f32x4){0.f, 0.f, 0.f, 0.f};
            f32x4 sc1 = (f32x4){0.f, 0.f, 0.f, 0.f};
#pragma unroll
            for (int f = 0; f < 2; ++f) {
                const int cb = f * 64 + lg * 16;
                bf16x8 k0 = *(const bf16x8*)((const char*)Ks + lm * 128 + (cb ^ xk));
                bf16x8 k1 = *(const bf16x8*)((const char*)Ks + (16 + lm) * 128 + (cb ^ xk));
                sc0 = __builtin_amdgcn_mfma_f32_16x16x32_bf16(qf[f], k0, sc0, 0, 0, 0);
                sc1 = __builtin_amdgcn_mfma_f32_16x16x32_bf16(qf[f], k1, sc1, 0, 0, 0);
            }
            float sv0[4], sv1[4], tm[4];
#pragma unroll
            for (int r = 0; r < 4; ++r) {
                const int t = tw + lg * 4 + r;
                sv0[r] = sc0[r] * 0.125f + ((s0 + lm) <= t ? 0.f : -1e9f);
                sv1[r] = sc1[r] * 0.125f + ((s0 + 16 + lm) <= t ? 0.f : -1e9f);
                tm[r] = fmaxf(sv0[r], sv1[r]);
            }
#pragma unroll
            for (int off = 1; off < 16; off <<= 1)
#pragma unroll
                for (int r = 0; r < 4; ++r) tm[r] = fmaxf(tm[r], __shfl_xor(tm[r], off));
            float fac[4], rs[4];
#pragma unroll
            for (int r = 0; r < 4; ++r) {
                const float mn = fmaxf(m_run[r], tm[r]);
                fac[r] = __expf(m_run[r] - mn);
                m_run[r] = mn;
                const float p0 = __expf(sv0[r] - mn);
                const float p1 = __expf(sv1[r] - mn);
                P[wave][lg * 4 + r][lm] = f2b(p0);
                P[wave][lg * 4 + r][16 + lm] = f2b(p1);
                rs[r] = p0 + p1;
            }
#pragma unroll
            for (int off = 1; off < 16; off <<= 1)
#pragma unroll
                for (int r = 0; r < 4; ++r) rs[r] += __shfl_xor(rs[r], off);
#pragma unroll
            for (int r = 0; r < 4; ++r) l_run[r] = l_run[r] * fac[r] + rs[r];
#pragma unroll
            for (int nt = 0; nt < 4; ++nt)
#pragma unroll
                for (int r = 0; r < 4; ++r) oacc[nt][r] *= fac[r];
            const bf16x8 pf = *(const bf16x8*)&P[wave][lm][lg * 8];
#pragma unroll
            for (int nt = 0; nt < 4; ++nt) {
                const bf16x8 vf = *(const bf16x8*)&Vt[nt * 16 + lm][lg * 8];
                oacc[nt] = __builtin_amdgcn_mfma_f32_16x16x32_bf16(pf, vf, oacc[nt], 0, 0, 0);
            }
        }
    }
#pragma unroll
    for (int nt = 0; nt < 4; ++nt)
#pragma unroll
        for (int r = 0; r < 4; ++r)
            out[(size_t)(b * TT + tw + lg * 4 + r) * DD + h * 64 + nt * 16 + lm] =
                f2b(oacc[nt][r] / l_run[r]);
}

// ================= fused residual + LayerNorm =================
template <bool R1B>
__global__ __launch_bounds__(256) void add_ln(
    const void* __restrict__ R1v, const u16* __restrict__ R2,
    const float* __restrict__ g, const float* __restrict__ bta,
    float* __restrict__ outf, u16* __restrict__ outb) {
    const int row = blockIdx.x, tid = threadIdx.x;
    float x0, x1;
    if constexpr (R1B) {
        ushort2 a = ((const ushort2*)((const u16*)R1v + (size_t)row * DD))[tid];
        x0 = b2f(a.x); x1 = b2f(a.y);
    } else {
        float2 a = ((const float2*)((const float*)R1v + (size_t)row * DD))[tid];
        x0 = a.x; x1 = a.y;
    }
    ushort2 c = ((const ushort2*)(R2 + (size_t)row * DD))[tid];
    x0 += b2f(c.x); x1 += b2f(c.y);

    __shared__ float2 red[256];
    red[tid] = make_float2(x0 + x1, x0 * x0 + x1 * x1);
    __syncthreads();
#pragma unroll
    for (int o = 128; o > 0; o >>= 1) {
        if (tid < o) {
            red[tid].x += red[tid + o].x;
            red[tid].y += red[tid + o].y;
        }
        __syncthreads();
    }
    const float mean = red[0].x * (1.f / 512.f);
    const float var = red[0].y * (1.f / 512.f) - mean * mean;
    const float rstd = rsqrtf(var + 1e-5f);
    const int i = tid * 2;
    const float y0 = (x0 - mean) * rstd * g[i] + bta[i];
    const float y1 = (x1 - mean) * rstd * g[i + 1] + bta[i + 1];
    if (outf) ((float2*)(outf + (size_t)row * DD))[tid] = make_float2(y0, y1);
    if (outb) {
        ushort2 ub; ub.x = f2b(y0); ub.y = f2b(y1);
        ((ushort2*)(outb + (size_t)row * DD))[tid] = ub;
    }
}

// ==== LN3 with fused split-K reduce: x = X2 + (P0 + P1 + bias) ====
__global__ __launch_bounds__(256) void add_ln_sk(
    const u16* __restrict__ X2, const float* __restrict__ P0,
    const float* __restrict__ P1, const float* __restrict__ fb,
    const float* __restrict__ g, const float* __restrict__ bta,
    float* __restrict__ outf) {
    const int row = blockIdx.x, tid = threadIdx.x;
    ushort2 a = ((const ushort2*)(X2 + (size_t)row * DD))[tid];
    float2 p0 = ((const float2*)(P0 + (size_t)row * DD))[tid];
    float2 p1 = ((const float2*)(P1 + (size_t)row * DD))[tid];
    const int i = tid * 2;
    float x0 = b2f(a.x) + p0.x + p1.x + fb[i];
    float x1 = b2f(a.y) + p0.y + p1.y + fb[i + 1];

    __shared__ float2 red[256];
    red[tid] = make_float2(x0 + x1, x0 * x0 + x1 * x1);
    __syncthreads();
#pragma unroll
    for (int o = 128; o > 0; o >>= 1) {
        if (tid < o) {
            red[tid].x += red[tid + o].x;
            red[tid].y += red[tid + o].y;
        }
        __syncthreads();
    }
    const float mean = red[0].x * (1.f / 512.f);
    const float var = red[0].y * (1.f / 512.f) - mean * mean;
    const float rstd = rsqrtf(var + 1e-5f);
    const float y0 = (x0 - mean) * rstd * g[i] + bta[i];
    const float y1 = (x1 - mean) * rstd * g[i + 1] + bta[i + 1];
    ((float2*)(outf + (size_t)row * DD))[tid] = make_float2(y0, y1);
}

extern "C" void kernel_launch(void* const* d_in, const int* in_sizes, int n_in,
                              void* d_out, int out_size, void* d_ws, size_t ws_size,
                              hipStream_t stream) {
    const float* tgt      = (const float*)d_in[0];
    const float* memory   = (const float*)d_in[1];
    const float* gate     = (const float*)d_in[3];
    const float* sa_in_w  = (const float*)d_in[4];
    const float* sa_in_b  = (const float*)d_in[5];
    const float* sa_out_w = (const float*)d_in[6];
    const float* sa_out_b = (const float*)d_in[7];
    const float* ca_in_w  = (const float*)d_in[8];
    const float* ca_in_b  = (const float*)d_in[9];
    const float* ca_out_w = (const float*)d_in[10];
    const float* ca_out_b = (const float*)d_in[11];
    const float* ff1_w    = (const float*)d_in[12];
    const float* ff1_b    = (const float*)d_in[13];
    const float* ff2_w    = (const float*)d_in[14];
    const float* ff2_b    = (const float*)d_in[15];
    const float* ln1_g    = (const float*)d_in[16];
    const float* ln1_b    = (const float*)d_in[17];
    const float* ln2_g    = (const float*)d_in[18];
    const float* ln2_b    = (const float*)d_in[19];
    const float* ln3_g    = (const float*)d_in[20];
    const float* ln3_b    = (const float*)d_in[21];

    // ---- workspace layout (u16 units) ----
    u16* ws16     = (u16*)d_ws;
    u16* QKVb     = ws16;                    // 6291456
    u16* sa_preb  = ws16 + 6291456;          // 2097152
    u16* PRJb     = ws16 + 8388608;          // 2097152
    u16* X1b      = ws16 + 10485760;         // 2097152
    u16* memb     = ws16 + 12582912;         // 2097152
    u16* CQb      = ws16 + 14680064;         // 2097152
    u16* CVb      = ws16 + 16777216;         // 2097152
    u16* QW       = ws16 + 18874368;         // 16777216 (4096 x 4096)
    u16* ca_preb  = ws16 + 35651584;         // 2097152
    u16* PRJ2b    = ws16 + 37748736;         // 2097152
    u16* X2b      = ws16 + 39845888;         // 2097152
    u16* HHb      = ws16 + 41943040;         // 8388608
    u16* Wreg     = ws16 + 52428800;
    u16* sa_in_wb = Wreg;                    // 786432
    u16* sa_out_wb= Wreg + 786432;           // 262144
    u16* ca_wq_b  = Wreg + 1048576;          // 262144
    u16* ca_wv_b  = Wreg + 1310720;          // 262144
    u16* WkT      = Wreg + 1572864;          // 262144
    u16* ca_out_wb= Wreg + 1835008;          // 262144
    u16* ff1_wb   = Wreg + 2097152;          // 1048576
    u16* ff2_wb   = Wreg + 3145728;          // 1048576
    u16* tgtb     = ws16 + 56623104;         // 2097152
    u16* SCb      = ws16 + 58720256;         // 16777216 bf16 (cross scores)
    float* FP     = (float*)SCb;             // reuse: ff2 split-K partials (f32, disjoint)
    float* outf   = (float*)d_out;

    const dim3 blk(256);

    // 0. casts (+ fused WkT transpose)
    CastSegs sg;
    sg.s[0]=tgt; sg.s[1]=memory; sg.s[2]=sa_in_w; sg.s[3]=sa_out_w;
    sg.s[4]=ca_in_w; sg.s[5]=ca_in_w + (size_t)1024*512; sg.s[6]=ca_out_w;
    sg.s[7]=ff1_w; sg.s[8]=ff2_w;
    sg.d[0]=tgtb; sg.d[1]=memb; sg.d[2]=sa_in_wb; sg.d[3]=sa_out_wb;
    sg.d[4]=ca_wq_b; sg.d[5]=ca_wv_b; sg.d[6]=ca_out_wb;
    sg.d[7]=ff1_wb; sg.d[8]=ff2_wb;
    sg.wsrc = ca_in_w; sg.wdst = WkT;
    {
        const int n4[9] = {524288,524288,196608,65536,65536,65536,65536,262144,262144};
        int c = 0;
        for (int i = 0; i < 9; ++i) { sg.cum[i] = c; c += n4[i]; }
        sg.cum[9] = c;
    }
    cast_multi<<<2048, blk, 0, stream>>>(sg);

    // 1. QKV (4096,1536) — 128x64 tile, 768 blocks, 3 blocks/CU
    gemm_bf16<128,64,false,false><<<dim3(24,32,1), blk, 0, stream>>>(
        tgtb,512,0, sa_in_wb,512,0, sa_in_b,sa_in_b,nullptr,
        QKVb,1536,0, 512, 1.f,1.f);
    // 2. self flash -> sa_preb
    flash_self<<<dim3(8,8,8), blk, 0, stream>>>(QKVb, sa_preb);
    // 3. proj1
    gemm_bf16<64,64,false,false><<<dim3(8,64,1), blk, 0, stream>>>(
        sa_preb,512,0, sa_out_wb,512,0, sa_out_b,sa_out_b,nullptr,
        PRJb,512,0, 512, 1.f,1.f);
    // 4. LN1 -> X1b
    add_ln<false><<<4096, blk, 0, stream>>>(tgt, PRJb, ln1_g, ln1_b, nullptr, X1b);
    // 5. cq (z=0, alpha .125) + cv (z=1) batched
    gemm_bf16<64,64,false,false><<<dim3(8,64,2), blk, 0, stream>>>(
        X1b,512,2097152, ca_wq_b,512,262144, ca_in_b, ca_in_b+1024, nullptr,
        CQb,512,2097152, 512, 0.125f, 1.f);
    // 6. qWg all heads (z=8, K=64) -> QW (4096,4096)
    gemm_bf16<64,64,false,true><<<dim3(8,64,8), blk, 0, stream>>>(
        CQb,512,64, WkT,64,32768, nullptr,nullptr,gate,
        QW,4096,512, 64, 1.f,1.f);
    // 7a. cross scores (bf16) -> SCb
    gemm_scores<<<dim3(4,4,64), blk, 0, stream>>>(QW, memb, SCb);
    // 7b. softmax + PV -> ca_preb
    softmax_pv<<<dim3(8,8,8), blk, 0, stream>>>(SCb, CVb, ca_preb);
    // 8. proj2
    gemm_bf16<64,64,false,false><<<dim3(8,64,1), blk, 0, stream>>>(
        ca_preb,512,0, ca_out_wb,512,0, ca_out_b,ca_out_b,nullptr,
        PRJ2b,512,0, 512, 1.f,1.f);
    // 9. LN2 -> X2b
    add_ln<true><<<4096, blk, 0, stream>>>(X1b, PRJ2b, ln2_g, ln2_b, nullptr, X2b);
    // 10. ff1 + relu -> HHb — 128x64 tile, 1024 blocks, 3 blocks/CU
    gemm_bf16<128,64,true,false><<<dim3(32,32,1), blk, 0, stream>>>(
        X2b,512,0, ff1_wb,512,0, ff1_b,ff1_b,nullptr,
        HHb,2048,0, 512, 1.f,1.f);
    // 11. ff2 split-K=2: z selects K-half; f32 partials into FP
    gemm_bf16<64,64,false,false,float,false><<<dim3(8,64,2), blk, 0, stream>>>(
        HHb,2048,1024, ff2_wb,2048,1024, nullptr,nullptr,nullptr,
        FP,512,2097152, 1024, 1.f,1.f);
    // 12. LN3 with fused reduce + bias -> d_out
    add_ln_sk<<<4096, blk, 0, stream>>>(X2b, FP, FP + 2097152, ff2_b,
                                        ln3_g, ln3_b, outf);

    (void)in_sizes; (void)n_in; (void)out_size; (void)ws_size;
}

// Round 10
// 182.845 us; speedup vs baseline: 1.2421x; 1.0098x over previous
//
#include <hip/hip_runtime.h>
#include <hip/hip_bf16.h>

#define BB 8
#define TT 512
#define SS 512
#define DD 512
#define HH 8

typedef __attribute__((ext_vector_type(8))) short bf16x8;
typedef __attribute__((ext_vector_type(4))) float f32x4;
typedef unsigned short u16;

__device__ __forceinline__ u16 f2b(float f) {
    __hip_bfloat16 h = __float2bfloat16(f);
    return *reinterpret_cast<u16*>(&h);
}
__device__ __forceinline__ float b2f(u16 v) {
    unsigned int u = ((unsigned int)v) << 16;
    return __builtin_bit_cast(float, u);
}
__device__ __forceinline__ void g2lds16(const void* g, void* l) {
    __builtin_amdgcn_global_load_lds(
        (const __attribute__((address_space(1))) void*)g,
        (__attribute__((address_space(3))) void*)l, 16, 0, 0);
}
template <int N> __device__ __forceinline__ void waitvm();
template <> __device__ __forceinline__ void waitvm<0>()  { asm volatile("s_waitcnt vmcnt(0)" ::: "memory"); }
template <> __device__ __forceinline__ void waitvm<4>()  { asm volatile("s_waitcnt vmcnt(4)" ::: "memory"); }
template <> __device__ __forceinline__ void waitvm<6>()  { asm volatile("s_waitcnt vmcnt(6)" ::: "memory"); }
template <> __device__ __forceinline__ void waitvm<8>()  { asm volatile("s_waitcnt vmcnt(8)" ::: "memory"); }
__device__ __forceinline__ void barrier_raw() {
    asm volatile("" ::: "memory");
    __builtin_amdgcn_s_barrier();
    asm volatile("" ::: "memory");
}
// T1: bijective XCD-chunking remap (requires gridDim product % 8 == 0)
__device__ __forceinline__ void xcd_swz(int& bx, int& by, int& bz) {
    const int gx = gridDim.x, gy = gridDim.y, gz = gridDim.z;
    const int n = gx * gy * gz;
    const int flat = bx + gx * (by + gy * bz);
    const int q = n >> 3;
    const int nf = (flat & 7) * q + (flat >> 3);
    bx = nf % gx;
    const int r = nf / gx;
    by = r % gy;
    bz = r / gy;
}

// ========= multi-segment f32 -> bf16 cast (+ fused WkT transpose) =========
struct CastSegs {
    const float* s[9];
    u16* d[9];
    int cum[10];
    const float* wsrc;  // ca_in_w
    u16* wdst;          // WkT
};
__global__ __launch_bounds__(256) void cast_multi(CastSegs sg) {
    const int total = sg.cum[9];
    for (int i = blockIdx.x * 256 + threadIdx.x; i < total; i += gridDim.x * 256) {
        int k = 0;
#pragma unroll
        for (int j = 1; j < 9; ++j) k += (i >= sg.cum[j]);
        const int loc = i - sg.cum[k];
        float4 v = ((const float4*)sg.s[k])[loc];
        ushort4 u;
        u.x = f2b(v.x); u.y = f2b(v.y); u.z = f2b(v.z); u.w = f2b(v.w);
        ((ushort4*)sg.d[k])[loc] = u;
    }
    // WkT[h][d][e] = ca_in_w[(512 + h*64 + e)*512 + d]  (262144 elements)
    for (int idx = blockIdx.x * 256 + threadIdx.x; idx < 262144; idx += gridDim.x * 256) {
        const int h = idx >> 15, d = (idx >> 6) & 511, e = idx & 63;
        sg.wdst[idx] = f2b(sg.wsrc[(size_t)(512 + h * 64 + e) * 512 + d]);
    }
}

// ================= bf16 MFMA GEMM, dbuf prefetch, TM x TN tiles ==========
// C = epi(A(M,K) @ B(N,K)^T). 256 thr (2x2 waves).
template <int TM, int TN, bool RELU, bool GATE, typename OutT = u16, bool ADDBIAS = true>
__global__ __launch_bounds__(256) void gemm_bf16(
    const u16* __restrict__ A, int lda, long az,
    const u16* __restrict__ Bw, int ldb, long bz,
    const float* __restrict__ bias, const float* __restrict__ biasB,
    const float* __restrict__ gate,
    OutT* __restrict__ C, int ldo, long cz,
    int K, float alpha, float alphaB) {
    __shared__ __align__(16) u16 As[2][TM * 64];
    __shared__ __align__(16) u16 Bs[2][TN * 64];
    int bx = blockIdx.x, by = blockIdx.y, bzz = blockIdx.z;
    xcd_swz(bx, by, bzz);
    const int tid = threadIdx.x;
    const int wave = tid >> 6, lane = tid & 63;
    const int lm = lane & 15, lg = lane >> 4;
    const int wm = wave >> 1, wn = wave & 1;
    const int m0 = by * TM, n0 = bx * TN;
    A += (size_t)bzz * az;
    Bw += (size_t)bzz * bz;
    C += (size_t)bzz * cz;
    constexpr int MI = TM / 32;
    constexpr int FN = TN / 32;
    constexpr int LPS = MI + FN;

    f32x4 acc[MI][FN];
#pragma unroll
    for (int mi = 0; mi < MI; ++mi)
#pragma unroll
        for (int ni = 0; ni < FN; ++ni) acc[mi][ni] = (f32x4){0.f, 0.f, 0.f, 0.f};

    const int srow = lane >> 3;
    const int sbyte = ((lane & 7) << 4) ^ (srow << 4);
    const int xk = (lm & 7) << 4;

    auto stage = [&](int buf, int kt) {
#pragma unroll
        for (int j = 0; j < MI; ++j) {
            const int r = wave * (TM / 4) + j * 8;
            g2lds16((const char*)(A + (size_t)(m0 + r + srow) * lda + kt) + sbyte,
                    (char*)As[buf] + (size_t)r * 128);
        }
#pragma unroll
        for (int j = 0; j < FN; ++j) {
            const int r = wave * (TN / 4) + j * 8;
            g2lds16((const char*)(Bw + (size_t)(n0 + r + srow) * ldb + kt) + sbyte,
                    (char*)Bs[buf] + (size_t)r * 128);
        }
    };

    stage(0, 0);
    const int NK = K >> 6;
    for (int t = 0; t < NK; ++t) {
        const int cur = t & 1;
        if (t + 1 < NK) { stage(cur ^ 1, (t + 1) << 6); waitvm<LPS>(); }
        else            { waitvm<0>(); }
        barrier_raw();
#pragma unroll
        for (int kh = 0; kh < 2; ++kh) {
            const int cb = kh * 64 + lg * 16;
            bf16x8 af[MI], bfr[FN];
#pragma unroll
            for (int mi = 0; mi < MI; ++mi) {
                const int row = wm * (TM / 2) + mi * 16 + lm;
                af[mi] = *(const bf16x8*)((const char*)As[cur] + row * 128 + (cb ^ xk));
            }
#pragma unroll
            for (int ni = 0; ni < FN; ++ni) {
                const int row = wn * (TN / 2) + ni * 16 + lm;
                bfr[ni] = *(const bf16x8*)((const char*)Bs[cur] + row * 128 + (cb ^ xk));
            }
#pragma unroll
            for (int mi = 0; mi < MI; ++mi)
#pragma unroll
                for (int ni = 0; ni < FN; ++ni)
                    acc[mi][ni] = __builtin_amdgcn_mfma_f32_16x16x32_bf16(
                        af[mi], bfr[ni], acc[mi][ni], 0, 0, 0);
        }
        barrier_raw();
    }

    const float* bp = bzz ? biasB : bias;
    const float al = bzz ? alphaB : alpha;
#pragma unroll
    for (int mi = 0; mi < MI; ++mi)
#pragma unroll
        for (int ni = 0; ni < FN; ++ni)
#pragma unroll
            for (int r = 0; r < 4; ++r) {
                const int m = m0 + wm * (TM / 2) + mi * 16 + lg * 4 + r;
                const int n = n0 + wn * (TN / 2) + ni * 16 + lm;
                float v = acc[mi][ni][r];
                if constexpr (GATE) v *= gate[(size_t)(m & 511) * 512 + n];
                else if constexpr (ADDBIAS) v = (v + bp[n]) * al;
                if constexpr (RELU) v = fmaxf(v, 0.f);
                if constexpr (sizeof(OutT) == 2) C[(size_t)m * ldo + n] = (OutT)f2b(v);
                else                             C[(size_t)m * ldo + n] = v;
            }
}

// ======== cross scores batched GEMM: SC[b,h] = QW_h @ memb_b^T (bf16) ====
// 128x64 tile, 48KB LDS -> 3 blocks/CU, grid (8,4,64).
__global__ __launch_bounds__(256) void gemm_scores(
    const u16* __restrict__ QWp, const u16* __restrict__ membp,
    u16* __restrict__ SC) {
    __shared__ __align__(16) u16 As[2][128 * 64];
    __shared__ __align__(16) u16 Bs[2][64 * 64];
    int bx = blockIdx.x, by = blockIdx.y, bzz = blockIdx.z;
    xcd_swz(bx, by, bzz);
    const int tid = threadIdx.x;
    const int wave = tid >> 6, lane = tid & 63;
    const int lm = lane & 15, lg = lane >> 4;
    const int wm = wave >> 1, wn = wave & 1;
    const int m0 = by * 128, n0 = bx * 64;
    const int z = bzz, b = z >> 3, h = z & 7;
    const u16* A  = QWp + (size_t)b * TT * 4096 + h * 512;   // lda 4096
    const u16* Bw = membp + (size_t)b * SS * 512;            // ldb 512
    u16* C = SC + ((size_t)z << 18);

    f32x4 acc[4][2];
#pragma unroll
    for (int mi = 0; mi < 4; ++mi)
#pragma unroll
        for (int ni = 0; ni < 2; ++ni) acc[mi][ni] = (f32x4){0.f, 0.f, 0.f, 0.f};

    const int srow = lane >> 3;
    const int sbyte = ((lane & 7) << 4) ^ (srow << 4);
    const int xk = (lm & 7) << 4;

    auto stage = [&](int buf, int kt) {
#pragma unroll
        for (int j = 0; j < 4; ++j) {
            const int r = wave * 32 + j * 8;
            g2lds16((const char*)(A + (size_t)(m0 + r + srow) * 4096 + kt) + sbyte,
                    (char*)As[buf] + (size_t)r * 128);
        }
#pragma unroll
        for (int j = 0; j < 2; ++j) {
            const int r = wave * 16 + j * 8;
            g2lds16((const char*)(Bw + (size_t)(n0 + r + srow) * 512 + kt) + sbyte,
                    (char*)Bs[buf] + (size_t)r * 128);
        }
    };

    stage(0, 0);
    for (int t = 0; t < 8; ++t) {
        const int cur = t & 1;
        if (t + 1 < 8) { stage(cur ^ 1, (t + 1) << 6); waitvm<6>(); }
        else           { waitvm<0>(); }
        barrier_raw();
#pragma unroll
        for (int kh = 0; kh < 2; ++kh) {
            const int cb = kh * 64 + lg * 16;
            bf16x8 af[4], bfr[2];
#pragma unroll
            for (int mi = 0; mi < 4; ++mi) {
                const int row = wm * 64 + mi * 16 + lm;
                af[mi] = *(const bf16x8*)((const char*)As[cur] + row * 128 + (cb ^ xk));
            }
#pragma unroll
            for (int ni = 0; ni < 2; ++ni) {
                const int row = wn * 32 + ni * 16 + lm;
                bfr[ni] = *(const bf16x8*)((const char*)Bs[cur] + row * 128 + (cb ^ xk));
            }
#pragma unroll
            for (int mi = 0; mi < 4; ++mi)
#pragma unroll
                for (int ni = 0; ni < 2; ++ni)
                    acc[mi][ni] = __builtin_amdgcn_mfma_f32_16x16x32_bf16(
                        af[mi], bfr[ni], acc[mi][ni], 0, 0, 0);
        }
        barrier_raw();
    }
#pragma unroll
    for (int mi = 0; mi < 4; ++mi)
#pragma unroll
        for (int ni = 0; ni < 2; ++ni)
#pragma unroll
            for (int r = 0; r < 4; ++r) {
                const int m = m0 + wm * 64 + mi * 16 + lg * 4 + r;
                const int n = n0 + wn * 32 + ni * 16 + lm;
                C[(size_t)m * 512 + n] = f2b(acc[mi][ni][r]);
            }
}

// ======== softmax + PV: out[b,t,h*64+] = softmax(SC[b,h,t,:]) @ CV_h ======
// SC is bf16. Lane (lm,lg) holds row lm's cols {lg*8+32k+e}: PV A-fragments.
__global__ __launch_bounds__(256) void softmax_pv(
    const u16* __restrict__ SC, const u16* __restrict__ CV,
    u16* __restrict__ out) {
    int btx = blockIdx.x, bh = blockIdx.y, bb = blockIdx.z;
    xcd_swz(btx, bh, bb);
    const int t0 = btx * 64, h = bh, b = bb;
    const int tid = threadIdx.x, wave = tid >> 6, lane = tid & 63;
    const int lm = lane & 15, lg = lane >> 4;
    __shared__ __align__(16) u16 Vt[64 * 512];  // [d][s] swizzled, 64KB

    {
        const int sp = tid * 2;
#pragma unroll
        for (int c = 0; c < 8; ++c) {
            bf16x8 v0 = *(const bf16x8*)(CV + ((size_t)b * SS + sp) * 512 + h * 64 + c * 8);
            bf16x8 v1 = *(const bf16x8*)(CV + ((size_t)b * SS + sp + 1) * 512 + h * 64 + c * 8);
#pragma unroll
            for (int j = 0; j < 8; ++j) {
                const int d = c * 8 + j;
                const unsigned int pk = (unsigned int)(u16)v0[j] |
                                        ((unsigned int)(u16)v1[j] << 16);
                *(unsigned int*)((char*)Vt + ((d << 10) + ((sp * 2) ^ ((d & 7) << 4)))) = pk;
            }
        }
    }

    const int tw = t0 + wave * 16;
    const u16* srow = SC + ((size_t)(b * 8 + h) << 18) + (size_t)(tw + lm) * 512 + lg * 8;
    float sa[16][8];
#pragma unroll
    for (int k = 0; k < 16; ++k) {
        const bf16x8 sv = *(const bf16x8*)(srow + k * 32);
#pragma unroll
        for (int j = 0; j < 8; ++j) sa[k][j] = b2f((u16)sv[j]);
    }
    float mx = -3e38f;
#pragma unroll
    for (int k = 0; k < 16; ++k)
#pragma unroll
        for (int j = 0; j < 8; ++j) mx = fmaxf(mx, sa[k][j]);
    mx = fmaxf(mx, __shfl_xor(mx, 16));
    mx = fmaxf(mx, __shfl_xor(mx, 32));
    float sum = 0.f;
    bf16x8 pb[16];
#pragma unroll
    for (int k = 0; k < 16; ++k) {
#pragma unroll
        for (int j = 0; j < 8; ++j) {
            const float p = __expf(sa[k][j] - mx);
            sum += p;
            pb[k][j] = (short)f2b(p);
        }
    }
    sum += __shfl_xor(sum, 16);
    sum += __shfl_xor(sum, 32);

    __syncthreads();

    f32x4 o[4];
#pragma unroll
    for (int nt = 0; nt < 4; ++nt) o[nt] = (f32x4){0.f, 0.f, 0.f, 0.f};
#pragma unroll
    for (int k = 0; k < 16; ++k) {
#pragma unroll
        for (int nt = 0; nt < 4; ++nt) {
            const int d = nt * 16 + lm;
            const bf16x8 vf = *(const bf16x8*)((const char*)Vt +
                ((d << 10) + ((k * 64 + lg * 16) ^ ((d & 7) << 4))));
            o[nt] = __builtin_amdgcn_mfma_f32_16x16x32_bf16(pb[k], vf, o[nt], 0, 0, 0);
        }
    }
#pragma unroll
    for (int r = 0; r < 4; ++r) {
        const float rs = __shfl(sum, lg * 4 + r);
        const float inv = 1.f / rs;
#pragma unroll
        for (int nt = 0; nt < 4; ++nt)
            out[(size_t)(b * TT + tw + lg * 4 + r) * DD + h * 64 + nt * 16 + lm] =
                f2b(o[nt][r] * inv);
    }
}

// ================= self flash attention (verified r3) =================
__global__ __launch_bounds__(256) void flash_self(const u16* __restrict__ QKV,
                                                  u16* __restrict__ out) {
    int btx = blockIdx.x, bh = blockIdx.y, bb = blockIdx.z;
    xcd_swz(btx, bh, bb);
    const int t0 = btx * 64, h = bh, b = bb;
    const int tid = threadIdx.x, wave = tid >> 6, lane = tid & 63;
    const int lm = lane & 15, lg = lane >> 4;
    __shared__ __align__(16) u16 Ks[32 * 64];
    __shared__ __align__(16) u16 Vt[64][40];
    __shared__ __align__(16) u16 P[4][16][40];

    const int tw = t0 + wave * 16;
    const size_t qrow = (size_t)(b * TT + tw + lm) * 1536 + h * 64;
    bf16x8 qf[2];
    qf[0] = *(const bf16x8*)(QKV + qrow + lg * 8);
    qf[1] = *(const bf16x8*)(QKV + qrow + 32 + lg * 8);

    float m_run[4], l_run[4];
    f32x4 oacc[4];
#pragma unroll
    for (int r = 0; r < 4; ++r) { m_run[r] = -3e38f; l_run[r] = 0.f; }
#pragma unroll
    for (int nt = 0; nt < 4; ++nt) oacc[nt] = (f32x4){0.f, 0.f, 0.f, 0.f};

    const int srow = lane >> 3, sbyte = ((lane & 7) << 4) ^ (srow << 4);
    const int xk = (lm & 7) << 4;
    const int smax = t0 + 64;
    for (int s0 = 0; s0 < smax; s0 += 32) {
        if (s0) __syncthreads();
        g2lds16((const char*)(QKV + (size_t)(b * TT + s0 + wave * 8 + srow) * 1536 +
                              512 + h * 64) + sbyte,
                (char*)Ks + wave * 1024);
        {
            const int s = tid & 31, d0 = (tid >> 5) * 8;
            bf16x8 vv = *(const bf16x8*)(QKV + (size_t)(b * TT + s0 + s) * 1536 +
                                         1024 + h * 64 + d0);
#pragma unroll
            for (int j = 0; j < 8; ++j) Vt[d0 + j][s] = (u16)vv[j];
        }
        __syncthreads();
        if (s0 <= tw + 15) {
            f32x4 sc0 = (f32x4){0.f, 0.f, 0.f, 0.f};
            f32x4 sc1 = (f32x4){0.f, 0.f, 0.f, 0.f};
#pragma unroll
            for (int f = 0; f < 2; ++f) {
                const int cb = f * 64 + lg * 16;
                bf16x8 k0 = *(const bf16x8*)((const char*)Ks + lm * 128 + (cb ^ xk));
                bf16x8 k1 = *(const bf16x8*)((const char*)Ks + (16 + lm) * 128 + (cb ^ xk));
                sc0 = __builtin_amdgcn_mfma_f32_16x16x32_bf16(qf[f], k0, sc0, 0, 0, 0);
                sc1 = __builtin_amdgcn_mfma_f32_16x16x32_bf16(qf[f], k1, sc1, 0, 0, 0);
            }
            float sv0[4], sv1[4], tm[4];
#pragma unroll
            for (int r = 0; r < 4; ++r) {
                const int t = tw + lg * 4 + r;
                sv0[r] = sc0[r] * 0.125f + ((s0 + lm) <= t ? 0.f : -1e9f);
                sv1[r] = sc1[r] * 0.125f + ((s0 + 16 + lm) <= t ? 0.f : -1e9f);
                tm[r] = fmaxf(sv0[r], sv1[r]);
            }
#pragma unroll
            for (int off = 1; off < 16; off <<= 1)
#pragma unroll
                for (int r = 0; r < 4; ++r) tm[r] = fmaxf(tm[r], __shfl_xor(tm[r], off));
            float fac[4], rs[4];
#pragma unroll
            for (int r = 0; r < 4; ++r) {
                const float mn = fmaxf(m_run[r], tm[r]);
                fac[r] = __expf(m_run[r] - mn);
                m_run[r] = mn;
                const float p0 = __expf(sv0[r] - mn);
                const float p1 = __expf(sv1[r] - mn);
                P[wave][lg * 4 + r][lm] = f2b(p0);
                P[wave][lg * 4 + r][16 + lm] = f2b(p1);
                rs[r] = p0 + p1;
            }
#pragma unroll
            for (int off = 1; off < 16; off <<= 1)
#pragma unroll
                for (int r = 0; r < 4; ++r) rs[r] += __shfl_xor(rs[r], off);
#pragma unroll
            for (int r = 0; r < 4; ++r) l_run[r] = l_run[r] * fac[r] + rs[r];
#pragma unroll
            for (int nt = 0; nt < 4; ++nt)
#pragma unroll
                for (int r = 0; r < 4; ++r) oacc[nt][r] *= fac[r];
            const bf16x8 pf = *(const bf16x8*)&P[wave][lm][lg * 8];
#pragma unroll
            for (int nt = 0; nt < 4; ++nt) {
                const bf16x8 vf = *(const bf16x8*)&Vt[nt * 16 + lm][lg * 8];
                oacc[nt] = __builtin_amdgcn_mfma_f32_16x16x32_bf16(pf, vf, oacc[nt], 0, 0, 0);
            }
        }
    }
#pragma unroll
    for (int nt = 0; nt < 4; ++nt)
#pragma unroll
        for (int r = 0; r < 4; ++r)
            out[(size_t)(b * TT + tw + lg * 4 + r) * DD + h * 64 + nt * 16 + lm] =
                f2b(oacc[nt][r] / l_run[r]);
}

// ================= fused residual + LayerNorm =================
template <bool R1B>
__global__ __launch_bounds__(256) void add_ln(
    const void* __restrict__ R1v, const u16* __restrict__ R2,
    const float* __restrict__ g, const float* __restrict__ bta,
    float* __restrict__ outf, u16* __restrict__ outb) {
    const int row = blockIdx.x, tid = threadIdx.x;
    float x0, x1;
    if constexpr (R1B) {
        ushort2 a = ((const ushort2*)((const u16*)R1v + (size_t)row * DD))[tid];
        x0 = b2f(a.x); x1 = b2f(a.y);
    } else {
        float2 a = ((const float2*)((const float*)R1v + (size_t)row * DD))[tid];
        x0 = a.x; x1 = a.y;
    }
    ushort2 c = ((const ushort2*)(R2 + (size_t)row * DD))[tid];
    x0 += b2f(c.x); x1 += b2f(c.y);

    __shared__ float2 red[256];
    red[tid] = make_float2(x0 + x1, x0 * x0 + x1 * x1);
    __syncthreads();
#pragma unroll
    for (int o = 128; o > 0; o >>= 1) {
        if (tid < o) {
            red[tid].x += red[tid + o].x;
            red[tid].y += red[tid + o].y;
        }
        __syncthreads();
    }
    const float mean = red[0].x * (1.f / 512.f);
    const float var = red[0].y * (1.f / 512.f) - mean * mean;
    const float rstd = rsqrtf(var + 1e-5f);
    const int i = tid * 2;
    const float y0 = (x0 - mean) * rstd * g[i] + bta[i];
    const float y1 = (x1 - mean) * rstd * g[i + 1] + bta[i + 1];
    if (outf) ((float2*)(outf + (size_t)row * DD))[tid] = make_float2(y0, y1);
    if (outb) {
        ushort2 ub; ub.x = f2b(y0); ub.y = f2b(y1);
        ((ushort2*)(outb + (size_t)row * DD))[tid] = ub;
    }
}

// ==== LN3 with fused split-K reduce: x = X2 + (P0 + P1 + bias) ====
__global__ __launch_bounds__(256) void add_ln_sk(
    const u16* __restrict__ X2, const float* __restrict__ P0,
    const float* __restrict__ P1, const float* __restrict__ fb,
    const float* __restrict__ g, const float* __restrict__ bta,
    float* __restrict__ outf) {
    const int row = blockIdx.x, tid = threadIdx.x;
    ushort2 a = ((const ushort2*)(X2 + (size_t)row * DD))[tid];
    float2 p0 = ((const float2*)(P0 + (size_t)row * DD))[tid];
    float2 p1 = ((const float2*)(P1 + (size_t)row * DD))[tid];
    const int i = tid * 2;
    float x0 = b2f(a.x) + p0.x + p1.x + fb[i];
    float x1 = b2f(a.y) + p0.y + p1.y + fb[i + 1];

    __shared__ float2 red[256];
    red[tid] = make_float2(x0 + x1, x0 * x0 + x1 * x1);
    __syncthreads();
#pragma unroll
    for (int o = 128; o > 0; o >>= 1) {
        if (tid < o) {
            red[tid].x += red[tid + o].x;
            red[tid].y += red[tid + o].y;
        }
        __syncthreads();
    }
    const float mean = red[0].x * (1.f / 512.f);
    const float var = red[0].y * (1.f / 512.f) - mean * mean;
    const float rstd = rsqrtf(var + 1e-5f);
    const float y0 = (x0 - mean) * rstd * g[i] + bta[i];
    const float y1 = (x1 - mean) * rstd * g[i + 1] + bta[i + 1];
    ((float2*)(outf + (size_t)row * DD))[tid] = make_float2(y0, y1);
}

extern "C" void kernel_launch(void* const* d_in, const int* in_sizes, int n_in,
                              void* d_out, int out_size, void* d_ws, size_t ws_size,
                              hipStream_t stream) {
    const float* tgt      = (const float*)d_in[0];
    const float* memory   = (const float*)d_in[1];
    const float* gate     = (const float*)d_in[3];
    const float* sa_in_w  = (const float*)d_in[4];
    const float* sa_in_b  = (const float*)d_in[5];
    const float* sa_out_w = (const float*)d_in[6];
    const float* sa_out_b = (const float*)d_in[7];
    const float* ca_in_w  = (const float*)d_in[8];
    const float* ca_in_b  = (const float*)d_in[9];
    const float* ca_out_w = (const float*)d_in[10];
    const float* ca_out_b = (const float*)d_in[11];
    const float* ff1_w    = (const float*)d_in[12];
    const float* ff1_b    = (const float*)d_in[13];
    const float* ff2_w    = (const float*)d_in[14];
    const float* ff2_b    = (const float*)d_in[15];
    const float* ln1_g    = (const float*)d_in[16];
    const float* ln1_b    = (const float*)d_in[17];
    const float* ln2_g    = (const float*)d_in[18];
    const float* ln2_b    = (const float*)d_in[19];
    const float* ln3_g    = (const float*)d_in[20];
    const float* ln3_b    = (const float*)d_in[21];

    // ---- workspace layout (u16 units) ----
    u16* ws16     = (u16*)d_ws;
    u16* QKVb     = ws16;                    // 6291456
    u16* sa_preb  = ws16 + 6291456;          // 2097152
    u16* PRJb     = ws16 + 8388608;          // 2097152
    u16* X1b      = ws16 + 10485760;         // 2097152
    u16* memb     = ws16 + 12582912;         // 2097152
    u16* CQb      = ws16 + 14680064;         // 2097152
    u16* CVb      = ws16 + 16777216;         // 2097152
    u16* QW       = ws16 + 18874368;         // 16777216 (4096 x 4096)
    u16* ca_preb  = ws16 + 35651584;         // 2097152
    u16* PRJ2b    = ws16 + 37748736;         // 2097152
    u16* X2b      = ws16 + 39845888;         // 2097152
    u16* HHb      = ws16 + 41943040;         // 8388608
    u16* Wreg     = ws16 + 52428800;
    u16* sa_in_wb = Wreg;                    // 786432
    u16* sa_out_wb= Wreg + 786432;           // 262144
    u16* ca_wq_b  = Wreg + 1048576;          // 262144
    u16* ca_wv_b  = Wreg + 1310720;          // 262144
    u16* WkT      = Wreg + 1572864;          // 262144
    u16* ca_out_wb= Wreg + 1835008;          // 262144
    u16* ff1_wb   = Wreg + 2097152;          // 1048576
    u16* ff2_wb   = Wreg + 3145728;          // 1048576
    u16* tgtb     = ws16 + 56623104;         // 2097152
    u16* SCb      = ws16 + 58720256;         // 16777216 bf16 (cross scores)
    float* FP     = (float*)SCb;             // reuse: ff2 split-K partials (f32, disjoint)
    float* outf   = (float*)d_out;

    const dim3 blk(256);

    // 0. casts (+ fused WkT transpose)
    CastSegs sg;
    sg.s[0]=tgt; sg.s[1]=memory; sg.s[2]=sa_in_w; sg.s[3]=sa_out_w;
    sg.s[4]=ca_in_w; sg.s[5]=ca_in_w + (size_t)1024*512; sg.s[6]=ca_out_w;
    sg.s[7]=ff1_w; sg.s[8]=ff2_w;
    sg.d[0]=tgtb; sg.d[1]=memb; sg.d[2]=sa_in_wb; sg.d[3]=sa_out_wb;
    sg.d[4]=ca_wq_b; sg.d[5]=ca_wv_b; sg.d[6]=ca_out_wb;
    sg.d[7]=ff1_wb; sg.d[8]=ff2_wb;
    sg.wsrc = ca_in_w; sg.wdst = WkT;
    {
        const int n4[9] = {524288,524288,196608,65536,65536,65536,65536,262144,262144};
        int c = 0;
        for (int i = 0; i < 9; ++i) { sg.cum[i] = c; c += n4[i]; }
        sg.cum[9] = c;
    }
    cast_multi<<<2048, blk, 0, stream>>>(sg);

    // 1. QKV (4096,1536) — 128x64 tile, 768 blocks, 3 blocks/CU
    gemm_bf16<128,64,false,false><<<dim3(24,32,1), blk, 0, stream>>>(
        tgtb,512,0, sa_in_wb,512,0, sa_in_b,sa_in_b,nullptr,
        QKVb,1536,0, 512, 1.f,1.f);
    // 2. self flash -> sa_preb
    flash_self<<<dim3(8,8,8), blk, 0, stream>>>(QKVb, sa_preb);
    // 3. proj1
    gemm_bf16<64,64,false,false><<<dim3(8,64,1), blk, 0, stream>>>(
        sa_preb,512,0, sa_out_wb,512,0, sa_out_b,sa_out_b,nullptr,
        PRJb,512,0, 512, 1.f,1.f);
    // 4. LN1 -> X1b
    add_ln<false><<<4096, blk, 0, stream>>>(tgt, PRJb, ln1_g, ln1_b, nullptr, X1b);
    // 5. cq (z=0, alpha .125) + cv (z=1) batched
    gemm_bf16<64,64,false,false><<<dim3(8,64,2), blk, 0, stream>>>(
        X1b,512,2097152, ca_wq_b,512,262144, ca_in_b, ca_in_b+1024, nullptr,
        CQb,512,2097152, 512, 0.125f, 1.f);
    // 6. qWg all heads (z=8, K=64) -> QW (4096,4096)
    gemm_bf16<64,64,false,true><<<dim3(8,64,8), blk, 0, stream>>>(
        CQb,512,64, WkT,64,32768, nullptr,nullptr,gate,
        QW,4096,512, 64, 1.f,1.f);
    // 7a. cross scores (bf16) -> SCb — 128x64 tile, 2048 blocks, 3/CU
    gemm_scores<<<dim3(8,4,64), blk, 0, stream>>>(QW, memb, SCb);
    // 7b. softmax + PV -> ca_preb
    softmax_pv<<<dim3(8,8,8), blk, 0, stream>>>(SCb, CVb, ca_preb);
    // 8. proj2
    gemm_bf16<64,64,false,false><<<dim3(8,64,1), blk, 0, stream>>>(
        ca_preb,512,0, ca_out_wb,512,0, ca_out_b,ca_out_b,nullptr,
        PRJ2b,512,0, 512, 1.f,1.f);
    // 9. LN2 -> X2b
    add_ln<true><<<4096, blk, 0, stream>>>(X1b, PRJ2b, ln2_g, ln2_b, nullptr, X2b);
    // 10. ff1 + relu -> HHb — 128x64 tile, 1024 blocks, 3 blocks/CU
    gemm_bf16<128,64,true,false><<<dim3(32,32,1), blk, 0, stream>>>(
        X2b,512,0, ff1_wb,512,0, ff1_b,ff1_b,nullptr,
        HHb,2048,0, 512, 1.f,1.f);
    // 11. ff2 split-K=2: z selects K-half; f32 partials into FP
    gemm_bf16<64,64,false,false,float,false><<<dim3(8,64,2), blk, 0, stream>>>(
        HHb,2048,1024, ff2_wb,2048,1024, nullptr,nullptr,nullptr,
        FP,512,2097152, 1024, 1.f,1.f);
    // 12. LN3 with fused reduce + bias -> d_out
    add_ln_sk<<<4096, blk, 0, stream>>>(X2b, FP, FP + 2097152, ff2_b,
                                        ln3_g, ln3_b, outf);

    (void)in_sizes; (void)n_in; (void)out_size; (void)ws_size;
}